// Round 5
// baseline (467.605 us; speedup 1.0000x reference)
//
#include <hip/hip_runtime.h>
#include <stdint.h>

// Koopman autoencoder — round 5 (MI355X / gfx950).
// 64-row waves (32 MFMA/wave/layer), persistent weights in VGPRs (col-sliced),
// 3-buffer LDS h rotation (input buf doubles as skip), f16 LDS-image
// intermediates (pe/pd) in ws, full-line NT final stores.

typedef _Float16 h8 __attribute__((ext_vector_type(8)));
typedef float    f4 __attribute__((ext_vector_type(4)));

#define ROWS_AUTO 104448
#define NT64      1632           // 64-row tiles in 104448 rows

// half-element offsets inside wt (all mats stored as W^T [n][k])
#define WT_ENCW      0
#define WT_ENCWOUT   (4*16384)
#define WT_DECW      (5*16384)
#define WT_DECWOUT   (9*16384)
#define WT_COMB      (10*16384)  // (WencI@WdecI)^T [128][128]

// ws byte offsets
#define MFULL_OFF_B 0x60000      // f16 [50][128][128] (WencI@L^{s+1}@WdecI)^T
#define ACH_OFF_B   0x200000     // f32 [50][441]
#define PE_OFF_B    0x220000     // f16 LDS-image tiles [1632][16384B]
#define PD_OFF_B    0x1C00000    // f16 LDS-image tiles [1632][16384B]

// k_enc/k_dec LDS: h0 h1 h2 (16KB each) + biases
#define H0 0
#define H1 16384
#define H2 32768
#define LDSE 51712
// k_pred LDS: hp h0 h1 h2 (8KB each) + biases
#define HP 0
#define P0 8192
#define P1 16384
#define P2 24576
#define LDSP 35328

#define hsw(rl, c) ((rl)*256 + ((((c)) ^ ((rl) & 7)) << 4))

__device__ __forceinline__ f4 mfma16(h8 a, h8 b, f4 c) {
  return __builtin_amdgcn_mfma_f32_16x16x32_f16(a, b, c, 0, 0, 0);
}
__device__ __forceinline__ h8 cvt8(f4 a, f4 b) {
  h8 r;
  r[0]=(_Float16)a[0]; r[1]=(_Float16)a[1]; r[2]=(_Float16)a[2]; r[3]=(_Float16)a[3];
  r[4]=(_Float16)b[0]; r[5]=(_Float16)b[1]; r[6]=(_Float16)b[2]; r[7]=(_Float16)b[3];
  return r;
}
// wave's 32-col slice of a 128x128 W^T
__device__ __forceinline__ void loadW(h8 B[8], const _Float16* gW, int nbase, int r15, int hi) {
#pragma unroll
  for (int nt = 0; nt < 2; ++nt)
#pragma unroll
    for (int ks = 0; ks < 4; ++ks)
      B[nt*4+ks] = *(const h8*)(gW + (size_t)(nbase + nt*16 + r15)*128 + ks*32 + hi*8);
}

// 64 rows x 128k @ regs-B -> acc[4][2]
__device__ __forceinline__ void mmF4(const char* sm, int hb, const h8 B[8],
                                     f4 acc[4][2], int r15, int hi) {
#pragma unroll
  for (int rt = 0; rt < 4; ++rt) { acc[rt][0] = (f4){0,0,0,0}; acc[rt][1] = (f4){0,0,0,0}; }
#pragma unroll
  for (int ks = 0; ks < 4; ++ks) {
    int c = ks*4 + hi;
    h8 a[4];
#pragma unroll
    for (int rt = 0; rt < 4; ++rt) a[rt] = *(const h8*)(sm + hb + hsw(rt*16 + r15, c));
#pragma unroll
    for (int rt = 0; rt < 4; ++rt) {
      acc[rt][0] = mfma16(a[rt], B[ks],   acc[rt][0]);
      acc[rt][1] = mfma16(a[rt], B[4+ks], acc[rt][1]);
    }
  }
}
// 32 rows variant
__device__ __forceinline__ void mmF2(const char* sm, int hb, const h8 B[8],
                                     f4 acc[2][2], int r15, int hi) {
#pragma unroll
  for (int rt = 0; rt < 2; ++rt) { acc[rt][0] = (f4){0,0,0,0}; acc[rt][1] = (f4){0,0,0,0}; }
#pragma unroll
  for (int ks = 0; ks < 4; ++ks) {
    int c = ks*4 + hi;
    h8 a0 = *(const h8*)(sm + hb + hsw(r15, c));
    h8 a1 = *(const h8*)(sm + hb + hsw(16 + r15, c));
    acc[0][0] = mfma16(a0, B[ks],   acc[0][0]);
    acc[0][1] = mfma16(a0, B[4+ks], acc[0][1]);
    acc[1][0] = mfma16(a1, B[ks],   acc[1][0]);
    acc[1][1] = mfma16(a1, B[4+ks], acc[1][1]);
  }
}

__device__ __forceinline__ void hw4(char* sm, int hb, int wbase, const f4 acc[4][2],
                                    const float* bl, int bo, int r15, int hi) {
#pragma unroll
  for (int nt = 0; nt < 2; ++nt) {
    int n = wbase + nt*16 + r15; float bv = bl[bo + n];
#pragma unroll
    for (int rt = 0; rt < 4; ++rt)
#pragma unroll
      for (int d = 0; d < 4; ++d) {
        int r = rt*16 + hi*4 + d;
        float v = fmaxf(acc[rt][nt][d] + bv, 0.f);
        *(_Float16*)(sm + hb + hsw(r, n >> 3) + (n & 7)*2) = (_Float16)v;
      }
  }
}
__device__ __forceinline__ void hw2(char* sm, int hb, int wbase, const f4 acc[2][2],
                                    const float* bl, int bo, int r15, int hi) {
#pragma unroll
  for (int nt = 0; nt < 2; ++nt) {
    int n = wbase + nt*16 + r15; float bv = bl[bo + n];
#pragma unroll
    for (int rt = 0; rt < 2; ++rt)
#pragma unroll
      for (int d = 0; d < 4; ++d) {
        int r = rt*16 + hi*4 + d;
        float v = fmaxf(acc[rt][nt][d] + bv, 0.f);
        *(_Float16*)(sm + hb + hsw(r, n >> 3) + (n & 7)*2) = (_Float16)v;
      }
  }
}

// ---------------- prep kernels ----------------

__global__ __launch_bounds__(512) void k_prep(
    const float* __restrict__ encW, const float* __restrict__ encWout,
    const float* __restrict__ decW, const float* __restrict__ decWout,
    const float* __restrict__ L,
    _Float16* __restrict__ wt, float* __restrict__ ach) {
  __shared__ float chA[441], chB[441];
  int m = blockIdx.y, tid = threadIdx.x;
  if (m == 10) {                                  // serial L-power chain
    if (blockIdx.x != 0) return;
    if (tid < 441) chA[tid] = L[tid];
    __syncthreads();
    for (int s = 0; s < 50; ++s) {
      if (tid < 441) ach[s*441 + tid] = chA[tid];
      if (s == 49) break;
      if (tid < 441) {
        int i = tid / 21, j = tid % 21; float a = 0.f;
        for (int k = 0; k < 21; ++k) a += chA[i*21 + k] * L[k*21 + j];
        chB[tid] = a;
      }
      __syncthreads();
      if (tid < 441) chA[tid] = chB[tid];
      __syncthreads();
    }
    return;
  }
  int idx = blockIdx.x*512 + tid;
  if (idx >= 16384) return;
  const float* src; _Float16* dst;
  if (m < 4)       { src = encW + m*16384;     dst = wt + WT_ENCW + m*16384; }
  else if (m == 4) { src = encWout;            dst = wt + WT_ENCWOUT; }
  else if (m < 9)  { src = decW + (m-5)*16384; dst = wt + WT_DECW + (m-5)*16384; }
  else             { src = decWout;            dst = wt + WT_DECWOUT; }
  int n = idx >> 7, k = idx & 127;
  dst[idx] = (_Float16)src[k*128 + n];            // W^T[n][k]
}

// block s<50: Mfull_s = WencI @ L^{s+1} @ WdecI ; s==50: Wcomb
__global__ __launch_bounds__(512) void k_aux(
    const float* __restrict__ ach, const float* __restrict__ wencI,
    const float* __restrict__ wdecI,
    _Float16* __restrict__ mfull, _Float16* __restrict__ wt) {
  __shared__ float T1[2688];
  __shared__ float sa[441];
  int s = blockIdx.x, t = threadIdx.x;
  if (s < 50) {
    if (t < 441) sa[t] = ach[s*441 + t];
    __syncthreads();
    for (int idx = t; idx < 2688; idx += 512) {
      int k = idx / 21, j = idx % 21;
      float a = 0.f;
      for (int u = 0; u < 21; ++u) a += wencI[k*21 + u] * sa[u*21 + j];
      T1[idx] = a;
    }
  } else {
    for (int idx = t; idx < 2688; idx += 512) T1[idx] = wencI[idx];
  }
  __syncthreads();
  _Float16* dst = (s < 50) ? (mfull + (size_t)s*16384) : (wt + WT_COMB);
  for (int idx = t; idx < 16384; idx += 512) {    // M^T[n][k]
    int n = idx >> 7, k = idx & 127;
    float a = 0.f;
    for (int j = 0; j < 21; ++j) a += T1[k*21 + j] * wdecI[j*128 + n];
    dst[idx] = (_Float16)a;
  }
}

// ---------------- encoder: x -> pe_ws, pd_ws (f16 LDS-images) ----------------

__global__ __launch_bounds__(256, 2) void k_enc(
    const float* __restrict__ x, const _Float16* __restrict__ wt,
    const float* __restrict__ enc_b, const float* __restrict__ enc_bout,
    _Float16* __restrict__ pe_ws, _Float16* __restrict__ pd_ws) {
  __shared__ char sm[LDSE];
  float* bl = (float*)(sm + 49152);
  int tid = threadIdx.x, lane = tid & 63;
  int r15 = lane & 15, hi = lane >> 4;
  int wbase = (tid >> 6) * 32;
  h8 B0[8], B1[8], B2[8], B3[8], B4[8];
  loadW(B1, wt + WT_ENCW + 16384,   wbase, r15, hi);
  loadW(B2, wt + WT_ENCW + 2*16384, wbase, r15, hi);
  loadW(B3, wt + WT_ENCW + 3*16384, wbase, r15, hi);
  loadW(B4, wt + WT_ENCWOUT,        wbase, r15, hi);
  bl[tid] = enc_b[tid]; bl[256 + tid] = enc_b[256 + tid];
  if (tid < 128) bl[512 + tid] = enc_bout[tid];
  f4 acc[4][2];

  for (int t = blockIdx.x; t < NT64; t += gridDim.x) {
    loadW(B0, wt + WT_ENCW, wbase, r15, hi);      // L0 (reloaded: comb clobbers B0)
    size_t rb = (size_t)t * 64;
#pragma unroll
    for (int i = 0; i < 4; ++i) {                 // stage x -> h0 (also the enc skip)
      int idx = i*256 + tid, rl = idx >> 4, c = idx & 15;
      const float* s = x + (rb + rl)*128 + c*8;
      f4 v0 = *(const f4*)s, v1 = *(const f4*)(s + 4);
      *(h8*)(sm + H0 + hsw(rl, c)) = cvt8(v0, v1);
    }
    __syncthreads();
    mmF4(sm, H0, B0, acc, r15, hi);
    loadW(B0, wt + WT_COMB, wbase, r15, hi);      // rotate B0 -> comb
    hw4(sm, H1, wbase, acc, bl, 0,   r15, hi); __syncthreads();
    mmF4(sm, H1, B1, acc, r15, hi); hw4(sm, H2, wbase, acc, bl, 128, r15, hi); __syncthreads();
    mmF4(sm, H2, B2, acc, r15, hi); hw4(sm, H1, wbase, acc, bl, 256, r15, hi); __syncthreads();
    mmF4(sm, H1, B3, acc, r15, hi); hw4(sm, H2, wbase, acc, bl, 384, r15, hi); __syncthreads();
    mmF4(sm, H2, B4, acc, r15, hi);               // encWout
    // pe = acc + bout + x(h0) -> h1 f16
#pragma unroll
    for (int nt = 0; nt < 2; ++nt) {
      int n = wbase + nt*16 + r15; float bv = bl[512 + n];
#pragma unroll
      for (int rt = 0; rt < 4; ++rt)
#pragma unroll
        for (int d = 0; d < 4; ++d) {
          int r = rt*16 + hi*4 + d;
          float sk = (float)*(const _Float16*)(sm + H0 + hsw(r, n >> 3) + (n & 7)*2);
          float v = acc[rt][nt][d] + bv + sk;
          *(_Float16*)(sm + H1 + hsw(r, n >> 3) + (n & 7)*2) = (_Float16)v;
        }
    }
    __syncthreads();
    {                                             // dump pe image
      char* g = (char*)(pe_ws) + (size_t)t*16384;
#pragma unroll
      for (int i = 0; i < 4; ++i) { int off = (i*256 + tid)*16;
        *(f4*)(g + off) = *(const f4*)(sm + H1 + off); }
    }
    mmF4(sm, H1, B0, acc, r15, hi);               // pd = pe @ comb
#pragma unroll
    for (int nt = 0; nt < 2; ++nt) {
      int n = wbase + nt*16 + r15;
#pragma unroll
      for (int rt = 0; rt < 4; ++rt)
#pragma unroll
        for (int d = 0; d < 4; ++d) {
          int r = rt*16 + hi*4 + d;
          *(_Float16*)(sm + H2 + hsw(r, n >> 3) + (n & 7)*2) = (_Float16)acc[rt][nt][d];
        }
    }
    __syncthreads();
    {                                             // dump pd image
      char* g = (char*)(pd_ws) + (size_t)t*16384;
#pragma unroll
      for (int i = 0; i < 4; ++i) { int off = (i*256 + tid)*16;
        *(f4*)(g + off) = *(const f4*)(sm + H2 + off); }
    }
  }
}

// ---------------- decoder: pe_ws -> out2, pd_ws -> out1 ----------------

__global__ __launch_bounds__(256, 2) void k_dec(
    const _Float16* __restrict__ wt, const _Float16* __restrict__ pe_ws,
    const _Float16* __restrict__ pd_ws,
    const float* __restrict__ dec_b, const float* __restrict__ dec_bout,
    float* __restrict__ out1, float* __restrict__ out2) {
  __shared__ char sm[LDSE];
  float* bl = (float*)(sm + 49152);
  int tid = threadIdx.x, lane = tid & 63;
  int r15 = lane & 15, hi = lane >> 4;
  int wbase = (tid >> 6) * 32;
  h8 B0[8], B1[8], B2[8], B3[8], B4[8];
  loadW(B0, wt + WT_DECW,           wbase, r15, hi);
  loadW(B1, wt + WT_DECW + 16384,   wbase, r15, hi);
  loadW(B2, wt + WT_DECW + 2*16384, wbase, r15, hi);
  loadW(B3, wt + WT_DECW + 3*16384, wbase, r15, hi);
  loadW(B4, wt + WT_DECWOUT,        wbase, r15, hi);
  bl[tid] = dec_b[tid]; bl[256 + tid] = dec_b[256 + tid];
  if (tid < 128) bl[512 + tid] = dec_bout[tid];
  f4 acc[4][2];

  for (int u = blockIdx.x; u < 2*NT64; u += gridDim.x) {
    int t = (u >= NT64) ? u - NT64 : u;
    const char* src = (const char*)((u >= NT64) ? pd_ws : pe_ws) + (size_t)t*16384;
    float* dst = ((u >= NT64) ? out1 : out2) + (size_t)t*64*128;
#pragma unroll
    for (int i = 0; i < 4; ++i) {                 // stage input image -> h0 (= skip)
      int off = (i*256 + tid)*16;
      *(f4*)(sm + H0 + off) = *(const f4*)(src + off);
    }
    __syncthreads();
    mmF4(sm, H0, B0, acc, r15, hi); hw4(sm, H1, wbase, acc, bl, 0,   r15, hi); __syncthreads();
    mmF4(sm, H1, B1, acc, r15, hi); hw4(sm, H2, wbase, acc, bl, 128, r15, hi); __syncthreads();
    mmF4(sm, H2, B2, acc, r15, hi); hw4(sm, H1, wbase, acc, bl, 256, r15, hi); __syncthreads();
    mmF4(sm, H1, B3, acc, r15, hi); hw4(sm, H2, wbase, acc, bl, 384, r15, hi); __syncthreads();
    mmF4(sm, H2, B4, acc, r15, hi);               // decWout
    __syncthreads();                              // all H2 reads done (trbuf = H1+H2)
#pragma unroll
    for (int nt = 0; nt < 2; ++nt) {              // out = acc + bout + skip -> trbuf f32
      int n = wbase + nt*16 + r15; float bv = bl[512 + n];
      int q = n >> 2;
#pragma unroll
      for (int rt = 0; rt < 4; ++rt)
#pragma unroll
        for (int d = 0; d < 4; ++d) {
          int r = rt*16 + hi*4 + d;
          float sk = (float)*(const _Float16*)(sm + H0 + hsw(r, n >> 3) + (n & 7)*2);
          float v = acc[rt][nt][d] + bv + sk;
          *(float*)(sm + H1 + r*512 + ((q ^ ((r & 7) << 2)) << 4) + (n & 3)*4) = v;
        }
    }
    __syncthreads();
    {                                             // full-line NT stores, 64 rows
      int rr = tid >> 2, qb = (tid & 3)*8;
#pragma unroll
      for (int i = 0; i < 8; ++i) {
        int q = qb + i;
        f4 v = *(const f4*)(sm + H1 + rr*512 + ((q ^ ((rr & 7) << 2)) << 4));
        __builtin_nontemporal_store(v, (f4*)(dst + (size_t)rr*128 + q*4));
      }
    }
  }
}

// ---------------- prediction: pe(t=0) @ Mfull_s -> dec -> out3 ----------------

__global__ __launch_bounds__(256, 2) void k_pred(
    const _Float16* __restrict__ pe_ws, const _Float16* __restrict__ wt,
    const _Float16* __restrict__ mfull,
    const float* __restrict__ dec_b, const float* __restrict__ dec_bout,
    float* __restrict__ out3) {
  __shared__ char sm[LDSP];
  float* bl = (float*)(sm + 32768);
  int tid = threadIdx.x, lane = tid & 63;
  int r15 = lane & 15, hi = lane >> 4;
  int wbase = (tid >> 6) * 32;
  h8 B0[8], B1[8], B2[8], B3[8], B4[8], Bm[8];
  loadW(B0, wt + WT_DECW,           wbase, r15, hi);
  loadW(B1, wt + WT_DECW + 16384,   wbase, r15, hi);
  loadW(B2, wt + WT_DECW + 2*16384, wbase, r15, hi);
  loadW(B3, wt + WT_DECW + 3*16384, wbase, r15, hi);
  loadW(B4, wt + WT_DECWOUT,        wbase, r15, hi);
  bl[tid] = dec_b[tid]; bl[256 + tid] = dec_b[256 + tid];
  if (tid < 128) bl[512 + tid] = dec_bout[tid];
  f4 acc[2][2];

  int rtile = blockIdx.x / 10, chunk = blockIdx.x % 10;  // 64 x 10 grid
#pragma unroll
  for (int i = 0; i < 2; ++i) {                   // stage pe t=0 rows -> hp (once)
    int idx = i*256 + tid, rl = idx >> 4, c = idx & 15;
    int rg = rtile*32 + rl;
    int r  = rg * 51;                             // pe row of t=0 sample rg
    const char* sp = (const char*)pe_ws + (size_t)(r >> 6)*16384
                   + (r & 63)*256 + ((c ^ ((r & 63) & 7)) << 4);
    *(f4*)(sm + HP + hsw(rl, c)) = *(const f4*)sp;
  }
  __syncthreads();

  for (int s = chunk*5; s < chunk*5 + 5; ++s) {
    loadW(Bm, mfull + (size_t)s*16384, wbase, r15, hi);
    mmF2(sm, HP, Bm, acc, r15, hi);               // di = pe_t0 @ Mfull_s
#pragma unroll
    for (int nt = 0; nt < 2; ++nt) {              // di -> h0 (also skip)
      int n = wbase + nt*16 + r15;
#pragma unroll
      for (int rt = 0; rt < 2; ++rt)
#pragma unroll
        for (int d = 0; d < 4; ++d) {
          int r = rt*16 + hi*4 + d;
          *(_Float16*)(sm + P0 + hsw(r, n >> 3) + (n & 7)*2) = (_Float16)acc[rt][nt][d];
        }
    }
    __syncthreads();
    mmF2(sm, P0, B0, acc, r15, hi); hw2(sm, P1, wbase, acc, bl, 0,   r15, hi); __syncthreads();
    mmF2(sm, P1, B1, acc, r15, hi); hw2(sm, P2, wbase, acc, bl, 128, r15, hi); __syncthreads();
    mmF2(sm, P2, B2, acc, r15, hi); hw2(sm, P1, wbase, acc, bl, 256, r15, hi); __syncthreads();
    mmF2(sm, P1, B3, acc, r15, hi); hw2(sm, P2, wbase, acc, bl, 384, r15, hi); __syncthreads();
    mmF2(sm, P2, B4, acc, r15, hi);               // decWout
    __syncthreads();                              // all P2 reads done (trbuf = P1+P2)
#pragma unroll
    for (int nt = 0; nt < 2; ++nt) {
      int n = wbase + nt*16 + r15; float bv = bl[512 + n];
      int q = n >> 2;
#pragma unroll
      for (int rt = 0; rt < 2; ++rt)
#pragma unroll
        for (int d = 0; d < 4; ++d) {
          int r = rt*16 + hi*4 + d;
          float sk = (float)*(const _Float16*)(sm + P0 + hsw(r, n >> 3) + (n & 7)*2);
          float v = acc[rt][nt][d] + bv + sk;
          *(float*)(sm + P1 + r*512 + ((q ^ ((r & 7) << 2)) << 4) + (n & 3)*4) = v;
        }
    }
    __syncthreads();
    {                                             // rows b -> out3[(b*50+s)*128]
      int rr = tid >> 3, qb = (tid & 7)*4;
      size_t b = (size_t)(rtile*32 + rr);
#pragma unroll
      for (int i = 0; i < 4; ++i) {
        int q = qb + i;
        f4 v = *(const f4*)(sm + P1 + rr*512 + ((q ^ ((rr & 7) << 2)) << 4));
        __builtin_nontemporal_store(v, (f4*)(out3 + (b*50 + s)*128 + q*4));
      }
    }
    __syncthreads();
  }
}

// ---------------- launch ----------------

extern "C" void kernel_launch(void* const* d_in, const int* in_sizes, int n_in,
                              void* d_out, int out_size, void* d_ws, size_t ws_size,
                              hipStream_t stream) {
  const float* x        = (const float*)d_in[0];
  const float* encW     = (const float*)d_in[1];
  const float* enc_b    = (const float*)d_in[2];
  const float* encWout  = (const float*)d_in[3];
  const float* enc_bout = (const float*)d_in[4];
  const float* decW     = (const float*)d_in[5];
  const float* dec_b    = (const float*)d_in[6];
  const float* decWout  = (const float*)d_in[7];
  const float* dec_bout = (const float*)d_in[8];
  const float* wencI    = (const float*)d_in[9];
  const float* L        = (const float*)d_in[10];
  const float* wdecI    = (const float*)d_in[11];

  char* ws = (char*)d_ws;
  _Float16* wt    = (_Float16*)ws;
  _Float16* mfull = (_Float16*)(ws + MFULL_OFF_B);
  float*    ach   = (float*)(ws + ACH_OFF_B);
  _Float16* pe_ws = (_Float16*)(ws + PE_OFF_B);
  _Float16* pd_ws = (_Float16*)(ws + PD_OFF_B);

  float* out1 = (float*)d_out;                       // autoencoder_output
  float* out2 = out1 + (size_t)ROWS_AUTO*128;        // outer_auto_output
  float* out3 = out2 + (size_t)ROWS_AUTO*128;        // predictions [2048][50][128]

  hipLaunchKernelGGL(k_prep, dim3(32, 11), dim3(512), 0, stream,
                     encW, encWout, decW, decWout, L, wt, ach);
  hipLaunchKernelGGL(k_aux, dim3(51), dim3(512), 0, stream,
                     ach, wencI, wdecI, mfull, wt);
  hipLaunchKernelGGL(k_enc, dim3(512), dim3(256), 0, stream,
                     x, wt, enc_b, enc_bout, pe_ws, pd_ws);
  hipLaunchKernelGGL(k_pred, dim3(640), dim3(256), 0, stream,
                     pe_ws, wt, mfull, dec_b, dec_bout, out3);
  hipLaunchKernelGGL(k_dec, dim3(512), dim3(256), 0, stream,
                     wt, pe_ws, pd_ws, dec_b, dec_bout, out1, out2);
}

// Round 6
// 429.862 us; speedup vs baseline: 1.0878x; 1.0878x over previous
//
#include <hip/hip_runtime.h>
#include <stdint.h>

// Koopman autoencoder — round 6 (MI355X / gfx950).
// R5 structure (64-row waves, persistent VGPR weights, 3-buffer LDS rotation,
// f16 LDS-image intermediates) with FIXED full-line store mappings
// (flat idx -> consecutive lanes cover consecutive 16B chunks) and 3 blocks/CU.

typedef _Float16 h8 __attribute__((ext_vector_type(8)));
typedef float    f4 __attribute__((ext_vector_type(4)));

#define ROWS_AUTO 104448
#define NT64      1632           // 64-row tiles in 104448 rows

// half-element offsets inside wt (all mats stored as W^T [n][k])
#define WT_ENCW      0
#define WT_ENCWOUT   (4*16384)
#define WT_DECW      (5*16384)
#define WT_DECWOUT   (9*16384)
#define WT_COMB      (10*16384)  // (WencI@WdecI)^T [128][128]

// ws byte offsets
#define MFULL_OFF_B 0x60000      // f16 [50][128][128] (WencI@L^{s+1}@WdecI)^T
#define ACH_OFF_B   0x200000     // f32 [50][441]
#define PE_OFF_B    0x220000     // f16 LDS-image tiles [1632][16384B]
#define PD_OFF_B    0x1C00000    // f16 LDS-image tiles [1632][16384B]

// k_enc/k_dec LDS: h0 h1 h2 (16KB each) + biases
#define H0 0
#define H1 16384
#define H2 32768
#define LDSE 51712
// k_pred LDS: hp h0 h1 h2 (8KB each) + biases
#define HP 0
#define P0 8192
#define P1 16384
#define P2 24576
#define LDSP 35328

#define hsw(rl, c) ((rl)*256 + ((((c)) ^ ((rl) & 7)) << 4))

__device__ __forceinline__ f4 mfma16(h8 a, h8 b, f4 c) {
  return __builtin_amdgcn_mfma_f32_16x16x32_f16(a, b, c, 0, 0, 0);
}
__device__ __forceinline__ h8 cvt8(f4 a, f4 b) {
  h8 r;
  r[0]=(_Float16)a[0]; r[1]=(_Float16)a[1]; r[2]=(_Float16)a[2]; r[3]=(_Float16)a[3];
  r[4]=(_Float16)b[0]; r[5]=(_Float16)b[1]; r[6]=(_Float16)b[2]; r[7]=(_Float16)b[3];
  return r;
}
// wave's 32-col slice of a 128x128 W^T
__device__ __forceinline__ void loadW(h8 B[8], const _Float16* gW, int nbase, int r15, int hi) {
#pragma unroll
  for (int nt = 0; nt < 2; ++nt)
#pragma unroll
    for (int ks = 0; ks < 4; ++ks)
      B[nt*4+ks] = *(const h8*)(gW + (size_t)(nbase + nt*16 + r15)*128 + ks*32 + hi*8);
}

// 64 rows x 128k @ regs-B -> acc[4][2]
__device__ __forceinline__ void mmF4(const char* sm, int hb, const h8 B[8],
                                     f4 acc[4][2], int r15, int hi) {
#pragma unroll
  for (int rt = 0; rt < 4; ++rt) { acc[rt][0] = (f4){0,0,0,0}; acc[rt][1] = (f4){0,0,0,0}; }
#pragma unroll
  for (int ks = 0; ks < 4; ++ks) {
    int c = ks*4 + hi;
    h8 a[4];
#pragma unroll
    for (int rt = 0; rt < 4; ++rt) a[rt] = *(const h8*)(sm + hb + hsw(rt*16 + r15, c));
#pragma unroll
    for (int rt = 0; rt < 4; ++rt) {
      acc[rt][0] = mfma16(a[rt], B[ks],   acc[rt][0]);
      acc[rt][1] = mfma16(a[rt], B[4+ks], acc[rt][1]);
    }
  }
}
// 32 rows variant
__device__ __forceinline__ void mmF2(const char* sm, int hb, const h8 B[8],
                                     f4 acc[2][2], int r15, int hi) {
#pragma unroll
  for (int rt = 0; rt < 2; ++rt) { acc[rt][0] = (f4){0,0,0,0}; acc[rt][1] = (f4){0,0,0,0}; }
#pragma unroll
  for (int ks = 0; ks < 4; ++ks) {
    int c = ks*4 + hi;
    h8 a0 = *(const h8*)(sm + hb + hsw(r15, c));
    h8 a1 = *(const h8*)(sm + hb + hsw(16 + r15, c));
    acc[0][0] = mfma16(a0, B[ks],   acc[0][0]);
    acc[0][1] = mfma16(a0, B[4+ks], acc[0][1]);
    acc[1][0] = mfma16(a1, B[ks],   acc[1][0]);
    acc[1][1] = mfma16(a1, B[4+ks], acc[1][1]);
  }
}

__device__ __forceinline__ void hw4(char* sm, int hb, int wbase, const f4 acc[4][2],
                                    const float* bl, int bo, int r15, int hi) {
#pragma unroll
  for (int nt = 0; nt < 2; ++nt) {
    int n = wbase + nt*16 + r15; float bv = bl[bo + n];
#pragma unroll
    for (int rt = 0; rt < 4; ++rt)
#pragma unroll
      for (int d = 0; d < 4; ++d) {
        int r = rt*16 + hi*4 + d;
        float v = fmaxf(acc[rt][nt][d] + bv, 0.f);
        *(_Float16*)(sm + hb + hsw(r, n >> 3) + (n & 7)*2) = (_Float16)v;
      }
  }
}
__device__ __forceinline__ void hw2(char* sm, int hb, int wbase, const f4 acc[2][2],
                                    const float* bl, int bo, int r15, int hi) {
#pragma unroll
  for (int nt = 0; nt < 2; ++nt) {
    int n = wbase + nt*16 + r15; float bv = bl[bo + n];
#pragma unroll
    for (int rt = 0; rt < 2; ++rt)
#pragma unroll
      for (int d = 0; d < 4; ++d) {
        int r = rt*16 + hi*4 + d;
        float v = fmaxf(acc[rt][nt][d] + bv, 0.f);
        *(_Float16*)(sm + hb + hsw(r, n >> 3) + (n & 7)*2) = (_Float16)v;
      }
  }
}

// ---------------- prep kernels ----------------

__global__ __launch_bounds__(512) void k_prep(
    const float* __restrict__ encW, const float* __restrict__ encWout,
    const float* __restrict__ decW, const float* __restrict__ decWout,
    const float* __restrict__ L,
    _Float16* __restrict__ wt, float* __restrict__ ach) {
  __shared__ float chA[441], chB[441];
  int m = blockIdx.y, tid = threadIdx.x;
  if (m == 10) {                                  // serial L-power chain
    if (blockIdx.x != 0) return;
    if (tid < 441) chA[tid] = L[tid];
    __syncthreads();
    for (int s = 0; s < 50; ++s) {
      if (tid < 441) ach[s*441 + tid] = chA[tid];
      if (s == 49) break;
      if (tid < 441) {
        int i = tid / 21, j = tid % 21; float a = 0.f;
        for (int k = 0; k < 21; ++k) a += chA[i*21 + k] * L[k*21 + j];
        chB[tid] = a;
      }
      __syncthreads();
      if (tid < 441) chA[tid] = chB[tid];
      __syncthreads();
    }
    return;
  }
  int idx = blockIdx.x*512 + tid;
  if (idx >= 16384) return;
  const float* src; _Float16* dst;
  if (m < 4)       { src = encW + m*16384;     dst = wt + WT_ENCW + m*16384; }
  else if (m == 4) { src = encWout;            dst = wt + WT_ENCWOUT; }
  else if (m < 9)  { src = decW + (m-5)*16384; dst = wt + WT_DECW + (m-5)*16384; }
  else             { src = decWout;            dst = wt + WT_DECWOUT; }
  int n = idx >> 7, k = idx & 127;
  dst[idx] = (_Float16)src[k*128 + n];            // W^T[n][k]
}

// block s<50: Mfull_s = WencI @ L^{s+1} @ WdecI ; s==50: Wcomb
__global__ __launch_bounds__(512) void k_aux(
    const float* __restrict__ ach, const float* __restrict__ wencI,
    const float* __restrict__ wdecI,
    _Float16* __restrict__ mfull, _Float16* __restrict__ wt) {
  __shared__ float T1[2688];
  __shared__ float sa[441];
  int s = blockIdx.x, t = threadIdx.x;
  if (s < 50) {
    if (t < 441) sa[t] = ach[s*441 + t];
    __syncthreads();
    for (int idx = t; idx < 2688; idx += 512) {
      int k = idx / 21, j = idx % 21;
      float a = 0.f;
      for (int u = 0; u < 21; ++u) a += wencI[k*21 + u] * sa[u*21 + j];
      T1[idx] = a;
    }
  } else {
    for (int idx = t; idx < 2688; idx += 512) T1[idx] = wencI[idx];
  }
  __syncthreads();
  _Float16* dst = (s < 50) ? (mfull + (size_t)s*16384) : (wt + WT_COMB);
  for (int idx = t; idx < 16384; idx += 512) {    // M^T[n][k]
    int n = idx >> 7, k = idx & 127;
    float a = 0.f;
    for (int j = 0; j < 21; ++j) a += T1[k*21 + j] * wdecI[j*128 + n];
    dst[idx] = (_Float16)a;
  }
}

// ---------------- encoder: x -> pe_ws, pd_ws (f16 LDS-images) ----------------

__global__ __launch_bounds__(256, 3) void k_enc(
    const float* __restrict__ x, const _Float16* __restrict__ wt,
    const float* __restrict__ enc_b, const float* __restrict__ enc_bout,
    _Float16* __restrict__ pe_ws, _Float16* __restrict__ pd_ws) {
  __shared__ char sm[LDSE];
  float* bl = (float*)(sm + 49152);
  int tid = threadIdx.x, lane = tid & 63;
  int r15 = lane & 15, hi = lane >> 4;
  int wbase = (tid >> 6) * 32;
  h8 B0[8], B1[8], B2[8], B3[8], B4[8];
  loadW(B1, wt + WT_ENCW + 16384,   wbase, r15, hi);
  loadW(B2, wt + WT_ENCW + 2*16384, wbase, r15, hi);
  loadW(B3, wt + WT_ENCW + 3*16384, wbase, r15, hi);
  loadW(B4, wt + WT_ENCWOUT,        wbase, r15, hi);
  bl[tid] = enc_b[tid]; bl[256 + tid] = enc_b[256 + tid];
  if (tid < 128) bl[512 + tid] = enc_bout[tid];
  f4 acc[4][2];

  for (int t = blockIdx.x; t < NT64; t += gridDim.x) {
    loadW(B0, wt + WT_ENCW, wbase, r15, hi);      // L0 (reloaded: comb clobbers B0)
    size_t rb = (size_t)t * 64;
#pragma unroll
    for (int i = 0; i < 4; ++i) {                 // stage x -> h0 (also the enc skip)
      int idx = i*256 + tid, rl = idx >> 4, c = idx & 15;
      const float* s = x + (rb + rl)*128 + c*8;
      f4 v0 = *(const f4*)s, v1 = *(const f4*)(s + 4);
      *(h8*)(sm + H0 + hsw(rl, c)) = cvt8(v0, v1);
    }
    __syncthreads();
    mmF4(sm, H0, B0, acc, r15, hi);
    loadW(B0, wt + WT_COMB, wbase, r15, hi);      // rotate B0 -> comb
    hw4(sm, H1, wbase, acc, bl, 0,   r15, hi); __syncthreads();
    mmF4(sm, H1, B1, acc, r15, hi); hw4(sm, H2, wbase, acc, bl, 128, r15, hi); __syncthreads();
    mmF4(sm, H2, B2, acc, r15, hi); hw4(sm, H1, wbase, acc, bl, 256, r15, hi); __syncthreads();
    mmF4(sm, H1, B3, acc, r15, hi); hw4(sm, H2, wbase, acc, bl, 384, r15, hi); __syncthreads();
    mmF4(sm, H2, B4, acc, r15, hi);               // encWout
    // pe = acc + bout + x(h0) -> h1 f16
#pragma unroll
    for (int nt = 0; nt < 2; ++nt) {
      int n = wbase + nt*16 + r15; float bv = bl[512 + n];
#pragma unroll
      for (int rt = 0; rt < 4; ++rt)
#pragma unroll
        for (int d = 0; d < 4; ++d) {
          int r = rt*16 + hi*4 + d;
          float sk = (float)*(const _Float16*)(sm + H0 + hsw(r, n >> 3) + (n & 7)*2);
          float v = acc[rt][nt][d] + bv + sk;
          *(_Float16*)(sm + H1 + hsw(r, n >> 3) + (n & 7)*2) = (_Float16)v;
        }
    }
    __syncthreads();
    {                                             // dump pe image (flat, full-line)
      char* g = (char*)(pe_ws) + (size_t)t*16384;
#pragma unroll
      for (int i = 0; i < 4; ++i) { int off = (i*256 + tid)*16;
        __builtin_nontemporal_store(*(const f4*)(sm + H1 + off), (f4*)(g + off)); }
    }
    mmF4(sm, H1, B0, acc, r15, hi);               // pd = pe @ comb
#pragma unroll
    for (int nt = 0; nt < 2; ++nt) {
      int n = wbase + nt*16 + r15;
#pragma unroll
      for (int rt = 0; rt < 4; ++rt)
#pragma unroll
        for (int d = 0; d < 4; ++d) {
          int r = rt*16 + hi*4 + d;
          *(_Float16*)(sm + H2 + hsw(r, n >> 3) + (n & 7)*2) = (_Float16)acc[rt][nt][d];
        }
    }
    __syncthreads();
    {                                             // dump pd image
      char* g = (char*)(pd_ws) + (size_t)t*16384;
#pragma unroll
      for (int i = 0; i < 4; ++i) { int off = (i*256 + tid)*16;
        __builtin_nontemporal_store(*(const f4*)(sm + H2 + off), (f4*)(g + off)); }
    }
  }
}

// ---------------- decoder: pe_ws -> out2, pd_ws -> out1 ----------------

__global__ __launch_bounds__(256, 3) void k_dec(
    const _Float16* __restrict__ wt, const _Float16* __restrict__ pe_ws,
    const _Float16* __restrict__ pd_ws,
    const float* __restrict__ dec_b, const float* __restrict__ dec_bout,
    float* __restrict__ out1, float* __restrict__ out2) {
  __shared__ char sm[LDSE];
  float* bl = (float*)(sm + 49152);
  int tid = threadIdx.x, lane = tid & 63;
  int r15 = lane & 15, hi = lane >> 4;
  int wbase = (tid >> 6) * 32;
  h8 B0[8], B1[8], B2[8], B3[8], B4[8];
  loadW(B0, wt + WT_DECW,           wbase, r15, hi);
  loadW(B1, wt + WT_DECW + 16384,   wbase, r15, hi);
  loadW(B2, wt + WT_DECW + 2*16384, wbase, r15, hi);
  loadW(B3, wt + WT_DECW + 3*16384, wbase, r15, hi);
  loadW(B4, wt + WT_DECWOUT,        wbase, r15, hi);
  bl[tid] = dec_b[tid]; bl[256 + tid] = dec_b[256 + tid];
  if (tid < 128) bl[512 + tid] = dec_bout[tid];
  f4 acc[4][2];

  for (int u = blockIdx.x; u < 2*NT64; u += gridDim.x) {
    int t = (u >= NT64) ? u - NT64 : u;
    const char* src = (const char*)((u >= NT64) ? pd_ws : pe_ws) + (size_t)t*16384;
    float* dst = ((u >= NT64) ? out1 : out2) + (size_t)t*64*128;
#pragma unroll
    for (int i = 0; i < 4; ++i) {                 // stage input image -> h0 (= skip)
      int off = (i*256 + tid)*16;
      *(f4*)(sm + H0 + off) = *(const f4*)(src + off);
    }
    __syncthreads();
    mmF4(sm, H0, B0, acc, r15, hi); hw4(sm, H1, wbase, acc, bl, 0,   r15, hi); __syncthreads();
    mmF4(sm, H1, B1, acc, r15, hi); hw4(sm, H2, wbase, acc, bl, 128, r15, hi); __syncthreads();
    mmF4(sm, H2, B2, acc, r15, hi); hw4(sm, H1, wbase, acc, bl, 256, r15, hi); __syncthreads();
    mmF4(sm, H1, B3, acc, r15, hi); hw4(sm, H2, wbase, acc, bl, 384, r15, hi); __syncthreads();
    mmF4(sm, H2, B4, acc, r15, hi);               // decWout
    __syncthreads();                              // all H2 reads done (trbuf = H1+H2)
#pragma unroll
    for (int nt = 0; nt < 2; ++nt) {              // out = acc + bout + skip -> trbuf f32
      int n = wbase + nt*16 + r15; float bv = bl[512 + n];
      int q = n >> 2;
#pragma unroll
      for (int rt = 0; rt < 4; ++rt)
#pragma unroll
        for (int d = 0; d < 4; ++d) {
          int r = rt*16 + hi*4 + d;
          float sk = (float)*(const _Float16*)(sm + H0 + hsw(r, n >> 3) + (n & 7)*2);
          float v = acc[rt][nt][d] + bv + sk;
          *(float*)(sm + H1 + r*512 + ((q ^ ((r & 7) << 2)) << 4) + (n & 3)*4) = v;
        }
    }
    __syncthreads();
    {                                             // FLAT full-line NT stores (fix)
#pragma unroll
      for (int i = 0; i < 8; ++i) {
        int idx = i*256 + tid, row = idx >> 5, q = idx & 31;
        f4 v = *(const f4*)(sm + H1 + row*512 + ((q ^ ((row & 7) << 2)) << 4));
        __builtin_nontemporal_store(v, (f4*)(dst + (size_t)row*128 + q*4));
      }
    }
  }
}

// ---------------- prediction: pe(t=0) @ Mfull_s -> dec -> out3 ----------------

__global__ __launch_bounds__(256, 4) void k_pred(
    const _Float16* __restrict__ pe_ws, const _Float16* __restrict__ wt,
    const _Float16* __restrict__ mfull,
    const float* __restrict__ dec_b, const float* __restrict__ dec_bout,
    float* __restrict__ out3) {
  __shared__ char sm[LDSP];
  float* bl = (float*)(sm + 32768);
  int tid = threadIdx.x, lane = tid & 63;
  int r15 = lane & 15, hi = lane >> 4;
  int wbase = (tid >> 6) * 32;
  h8 B0[8], B1[8], B2[8], B3[8], B4[8], Bm[8];
  loadW(B0, wt + WT_DECW,           wbase, r15, hi);
  loadW(B1, wt + WT_DECW + 16384,   wbase, r15, hi);
  loadW(B2, wt + WT_DECW + 2*16384, wbase, r15, hi);
  loadW(B3, wt + WT_DECW + 3*16384, wbase, r15, hi);
  loadW(B4, wt + WT_DECWOUT,        wbase, r15, hi);
  bl[tid] = dec_b[tid]; bl[256 + tid] = dec_b[256 + tid];
  if (tid < 128) bl[512 + tid] = dec_bout[tid];
  f4 acc[2][2];

  int rtile = blockIdx.x / 10, chunk = blockIdx.x % 10;  // 64 x 10 grid
#pragma unroll
  for (int i = 0; i < 2; ++i) {                   // stage pe t=0 rows -> hp (once)
    int idx = i*256 + tid, rl = idx >> 4, c = idx & 15;
    int rg = rtile*32 + rl;
    int r  = rg * 51;                             // pe row of t=0 sample rg
    const char* sp = (const char*)pe_ws + (size_t)(r >> 6)*16384
                   + (r & 63)*256 + ((c ^ ((r & 63) & 7)) << 4);
    *(f4*)(sm + HP + hsw(rl, c)) = *(const f4*)sp;
  }
  __syncthreads();

  for (int s = chunk*5; s < chunk*5 + 5; ++s) {
    loadW(Bm, mfull + (size_t)s*16384, wbase, r15, hi);
    mmF2(sm, HP, Bm, acc, r15, hi);               // di = pe_t0 @ Mfull_s
#pragma unroll
    for (int nt = 0; nt < 2; ++nt) {              // di -> h0 (also skip)
      int n = wbase + nt*16 + r15;
#pragma unroll
      for (int rt = 0; rt < 2; ++rt)
#pragma unroll
        for (int d = 0; d < 4; ++d) {
          int r = rt*16 + hi*4 + d;
          *(_Float16*)(sm + P0 + hsw(r, n >> 3) + (n & 7)*2) = (_Float16)acc[rt][nt][d];
        }
    }
    __syncthreads();
    mmF2(sm, P0, B0, acc, r15, hi); hw2(sm, P1, wbase, acc, bl, 0,   r15, hi); __syncthreads();
    mmF2(sm, P1, B1, acc, r15, hi); hw2(sm, P2, wbase, acc, bl, 128, r15, hi); __syncthreads();
    mmF2(sm, P2, B2, acc, r15, hi); hw2(sm, P1, wbase, acc, bl, 256, r15, hi); __syncthreads();
    mmF2(sm, P1, B3, acc, r15, hi); hw2(sm, P2, wbase, acc, bl, 384, r15, hi); __syncthreads();
    mmF2(sm, P2, B4, acc, r15, hi);               // decWout
    __syncthreads();                              // all P2 reads done (trbuf = P1+P2)
#pragma unroll
    for (int nt = 0; nt < 2; ++nt) {
      int n = wbase + nt*16 + r15; float bv = bl[512 + n];
      int q = n >> 2;
#pragma unroll
      for (int rt = 0; rt < 2; ++rt)
#pragma unroll
        for (int d = 0; d < 4; ++d) {
          int r = rt*16 + hi*4 + d;
          float sk = (float)*(const _Float16*)(sm + P0 + hsw(r, n >> 3) + (n & 7)*2);
          float v = acc[rt][nt][d] + bv + sk;
          *(float*)(sm + P1 + r*512 + ((q ^ ((r & 7) << 2)) << 4) + (n & 3)*4) = v;
        }
    }
    __syncthreads();
    {                                             // FLAT full-line NT stores (fix)
#pragma unroll
      for (int i = 0; i < 4; ++i) {
        int idx = i*256 + tid, row = idx >> 5, q = idx & 31;
        size_t b = (size_t)(rtile*32 + row);
        f4 v = *(const f4*)(sm + P1 + row*512 + ((q ^ ((row & 7) << 2)) << 4));
        __builtin_nontemporal_store(v, (f4*)(out3 + (b*50 + s)*128 + q*4));
      }
    }
    __syncthreads();
  }
}

// ---------------- launch ----------------

extern "C" void kernel_launch(void* const* d_in, const int* in_sizes, int n_in,
                              void* d_out, int out_size, void* d_ws, size_t ws_size,
                              hipStream_t stream) {
  const float* x        = (const float*)d_in[0];
  const float* encW     = (const float*)d_in[1];
  const float* enc_b    = (const float*)d_in[2];
  const float* encWout  = (const float*)d_in[3];
  const float* enc_bout = (const float*)d_in[4];
  const float* decW     = (const float*)d_in[5];
  const float* dec_b    = (const float*)d_in[6];
  const float* decWout  = (const float*)d_in[7];
  const float* dec_bout = (const float*)d_in[8];
  const float* wencI    = (const float*)d_in[9];
  const float* L        = (const float*)d_in[10];
  const float* wdecI    = (const float*)d_in[11];

  char* ws = (char*)d_ws;
  _Float16* wt    = (_Float16*)ws;
  _Float16* mfull = (_Float16*)(ws + MFULL_OFF_B);
  float*    ach   = (float*)(ws + ACH_OFF_B);
  _Float16* pe_ws = (_Float16*)(ws + PE_OFF_B);
  _Float16* pd_ws = (_Float16*)(ws + PD_OFF_B);

  float* out1 = (float*)d_out;                       // autoencoder_output
  float* out2 = out1 + (size_t)ROWS_AUTO*128;        // outer_auto_output
  float* out3 = out2 + (size_t)ROWS_AUTO*128;        // predictions [2048][50][128]

  hipLaunchKernelGGL(k_prep, dim3(32, 11), dim3(512), 0, stream,
                     encW, encWout, decW, decWout, L, wt, ach);
  hipLaunchKernelGGL(k_aux, dim3(51), dim3(512), 0, stream,
                     ach, wencI, wdecI, mfull, wt);
  hipLaunchKernelGGL(k_enc, dim3(768), dim3(256), 0, stream,
                     x, wt, enc_b, enc_bout, pe_ws, pd_ws);
  hipLaunchKernelGGL(k_pred, dim3(640), dim3(256), 0, stream,
                     pe_ws, wt, mfull, dec_b, dec_bout, out3);
  hipLaunchKernelGGL(k_dec, dim3(768), dim3(256), 0, stream,
                     wt, pe_ws, pd_ws, dec_b, dec_bout, out1, out2);
}

// Round 7
// 355.286 us; speedup vs baseline: 1.3161x; 1.2099x over previous
//
#include <hip/hip_runtime.h>
#include <stdint.h>

// Koopman autoencoder — round 7 (MI355X / gfx950).
// R6 structure with: (1) PLAIN full-line stores (NT hint caused ~214MB RFO
// fetch per kernel — fillBuffer evidence), (2) swapped-operand MFMA so each
// lane holds 4 consecutive output cols -> b64/b128 vectorized epilogues.

typedef _Float16 h8 __attribute__((ext_vector_type(8)));
typedef _Float16 h4 __attribute__((ext_vector_type(4)));
typedef float    f4 __attribute__((ext_vector_type(4)));

#define ROWS_AUTO 104448
#define NT64      1632           // 64-row tiles

// half-element offsets inside wt (all mats stored as W^T [n][k])
#define WT_ENCW      0
#define WT_ENCWOUT   (4*16384)
#define WT_DECW      (5*16384)
#define WT_DECWOUT   (9*16384)
#define WT_COMB      (10*16384)  // (WencI@WdecI)^T [128][128]

// ws byte offsets
#define MFULL_OFF_B 0x60000      // f16 [50][128][128] (WencI@L^{s+1}@WdecI)^T
#define ACH_OFF_B   0x200000     // f32 [50][441]
#define PE_OFF_B    0x220000     // f16 LDS-image tiles [1632][16384B]
#define PD_OFF_B    0x1C00000    // f16 LDS-image tiles [1632][16384B]

// k_enc/k_dec LDS: h0 h1 h2 (16KB each) + biases
#define H0 0
#define H1 16384
#define H2 32768
#define LDSE 51712
// k_pred LDS: hp p0 p1 p2 (8KB each) + biases
#define HP 0
#define P0 8192
#define P1 16384
#define P2 24576
#define LDSP 35328

#define hsw(rl, c) ((rl)*256 + ((((c)) ^ ((rl) & 7)) << 4))

__device__ __forceinline__ f4 mfma16(h8 a, h8 b, f4 c) {
  return __builtin_amdgcn_mfma_f32_16x16x32_f16(a, b, c, 0, 0, 0);
}
__device__ __forceinline__ h8 cvt8(f4 a, f4 b) {
  h8 r;
  r[0]=(_Float16)a[0]; r[1]=(_Float16)a[1]; r[2]=(_Float16)a[2]; r[3]=(_Float16)a[3];
  r[4]=(_Float16)b[0]; r[5]=(_Float16)b[1]; r[6]=(_Float16)b[2]; r[7]=(_Float16)b[3];
  return r;
}
// wave's 32-col slice of a 128x128 W^T (A-operand fragments)
__device__ __forceinline__ void loadW(h8 B[8], const _Float16* gW, int nbase, int r15, int hi) {
#pragma unroll
  for (int nt = 0; nt < 2; ++nt)
#pragma unroll
    for (int ks = 0; ks < 4; ++ks)
      B[nt*4+ks] = *(const h8*)(gW + (size_t)(nbase + nt*16 + r15)*128 + ks*32 + hi*8);
}

// SWAPPED: D = W_sliceT x h^T -> lane holds out[row=rt*16+r15][n=wbase+nt*16+hi*4+d]
__device__ __forceinline__ void mmF4s(const char* sm, int hb, const h8 B[8],
                                      f4 acc[4][2], int r15, int hi) {
#pragma unroll
  for (int rt = 0; rt < 4; ++rt) { acc[rt][0] = (f4){0,0,0,0}; acc[rt][1] = (f4){0,0,0,0}; }
#pragma unroll
  for (int ks = 0; ks < 4; ++ks) {
    int c = ks*4 + hi;
    h8 a[4];
#pragma unroll
    for (int rt = 0; rt < 4; ++rt) a[rt] = *(const h8*)(sm + hb + hsw(rt*16 + r15, c));
#pragma unroll
    for (int rt = 0; rt < 4; ++rt) {
      acc[rt][0] = mfma16(B[ks],   a[rt], acc[rt][0]);
      acc[rt][1] = mfma16(B[4+ks], a[rt], acc[rt][1]);
    }
  }
}
__device__ __forceinline__ void mmF2s(const char* sm, int hb, const h8 B[8],
                                      f4 acc[2][2], int r15, int hi) {
#pragma unroll
  for (int rt = 0; rt < 2; ++rt) { acc[rt][0] = (f4){0,0,0,0}; acc[rt][1] = (f4){0,0,0,0}; }
#pragma unroll
  for (int ks = 0; ks < 4; ++ks) {
    int c = ks*4 + hi;
    h8 a0 = *(const h8*)(sm + hb + hsw(r15, c));
    h8 a1 = *(const h8*)(sm + hb + hsw(16 + r15, c));
    acc[0][0] = mfma16(B[ks],   a0, acc[0][0]);
    acc[0][1] = mfma16(B[4+ks], a0, acc[0][1]);
    acc[1][0] = mfma16(B[ks],   a1, acc[1][0]);
    acc[1][1] = mfma16(B[4+ks], a1, acc[1][1]);
  }
}

// ReLU(acc + bias) -> h[hb] via b64 writes (4 consecutive halves per lane)
__device__ __forceinline__ void hw4s(char* sm, int hb, int wbase, const f4 acc[4][2],
                                     const float* bl, int bo, int r15, int hi) {
  f4 bb0 = *(const f4*)(bl + bo + wbase + hi*4);
  f4 bb1 = *(const f4*)(bl + bo + wbase + 16 + hi*4);
  int bo2 = (hi & 1) * 8;
#pragma unroll
  for (int nt = 0; nt < 2; ++nt) {
    int c = ((wbase + nt*16) >> 3) + (hi >> 1);
    f4 bb = nt ? bb1 : bb0;
#pragma unroll
    for (int rt = 0; rt < 4; ++rt) {
      int row = rt*16 + r15;
      h4 p;
#pragma unroll
      for (int d = 0; d < 4; ++d) p[d] = (_Float16)fmaxf(acc[rt][nt][d] + bb[d], 0.f);
      *(h4*)(sm + hb + row*256 + ((c ^ (row & 7)) << 4) + bo2) = p;
    }
  }
}
__device__ __forceinline__ void hw2s(char* sm, int hb, int wbase, const f4 acc[2][2],
                                     const float* bl, int bo, int r15, int hi) {
  f4 bb0 = *(const f4*)(bl + bo + wbase + hi*4);
  f4 bb1 = *(const f4*)(bl + bo + wbase + 16 + hi*4);
  int bo2 = (hi & 1) * 8;
#pragma unroll
  for (int nt = 0; nt < 2; ++nt) {
    int c = ((wbase + nt*16) >> 3) + (hi >> 1);
    f4 bb = nt ? bb1 : bb0;
#pragma unroll
    for (int rt = 0; rt < 2; ++rt) {
      int row = rt*16 + r15;
      h4 p;
#pragma unroll
      for (int d = 0; d < 4; ++d) p[d] = (_Float16)fmaxf(acc[rt][nt][d] + bb[d], 0.f);
      *(h4*)(sm + hb + row*256 + ((c ^ (row & 7)) << 4) + bo2) = p;
    }
  }
}

// ---------------- prep kernels ----------------

__global__ __launch_bounds__(512) void k_prep(
    const float* __restrict__ encW, const float* __restrict__ encWout,
    const float* __restrict__ decW, const float* __restrict__ decWout,
    const float* __restrict__ L,
    _Float16* __restrict__ wt, float* __restrict__ ach) {
  __shared__ float chA[441], chB[441];
  int m = blockIdx.y, tid = threadIdx.x;
  if (m == 10) {                                  // serial L-power chain
    if (blockIdx.x != 0) return;
    if (tid < 441) chA[tid] = L[tid];
    __syncthreads();
    for (int s = 0; s < 50; ++s) {
      if (tid < 441) ach[s*441 + tid] = chA[tid];
      if (s == 49) break;
      if (tid < 441) {
        int i = tid / 21, j = tid % 21; float a = 0.f;
        for (int k = 0; k < 21; ++k) a += chA[i*21 + k] * L[k*21 + j];
        chB[tid] = a;
      }
      __syncthreads();
      if (tid < 441) chA[tid] = chB[tid];
      __syncthreads();
    }
    return;
  }
  int idx = blockIdx.x*512 + tid;
  if (idx >= 16384) return;
  const float* src; _Float16* dst;
  if (m < 4)       { src = encW + m*16384;     dst = wt + WT_ENCW + m*16384; }
  else if (m == 4) { src = encWout;            dst = wt + WT_ENCWOUT; }
  else if (m < 9)  { src = decW + (m-5)*16384; dst = wt + WT_DECW + (m-5)*16384; }
  else             { src = decWout;            dst = wt + WT_DECWOUT; }
  int n = idx >> 7, k = idx & 127;
  dst[idx] = (_Float16)src[k*128 + n];            // W^T[n][k]
}

// block s<50: Mfull_s = WencI @ L^{s+1} @ WdecI ; s==50: Wcomb
__global__ __launch_bounds__(512) void k_aux(
    const float* __restrict__ ach, const float* __restrict__ wencI,
    const float* __restrict__ wdecI,
    _Float16* __restrict__ mfull, _Float16* __restrict__ wt) {
  __shared__ float T1[2688];
  __shared__ float sa[441];
  int s = blockIdx.x, t = threadIdx.x;
  if (s < 50) {
    if (t < 441) sa[t] = ach[s*441 + t];
    __syncthreads();
    for (int idx = t; idx < 2688; idx += 512) {
      int k = idx / 21, j = idx % 21;
      float a = 0.f;
      for (int u = 0; u < 21; ++u) a += wencI[k*21 + u] * sa[u*21 + j];
      T1[idx] = a;
    }
  } else {
    for (int idx = t; idx < 2688; idx += 512) T1[idx] = wencI[idx];
  }
  __syncthreads();
  _Float16* dst = (s < 50) ? (mfull + (size_t)s*16384) : (wt + WT_COMB);
  for (int idx = t; idx < 16384; idx += 512) {    // M^T[n][k]
    int n = idx >> 7, k = idx & 127;
    float a = 0.f;
    for (int j = 0; j < 21; ++j) a += T1[k*21 + j] * wdecI[j*128 + n];
    dst[idx] = (_Float16)a;
  }
}

// ---------------- encoder: x -> pe_ws, pd_ws (f16 LDS-images) ----------------

__global__ __launch_bounds__(256, 3) void k_enc(
    const float* __restrict__ x, const _Float16* __restrict__ wt,
    const float* __restrict__ enc_b, const float* __restrict__ enc_bout,
    _Float16* __restrict__ pe_ws, _Float16* __restrict__ pd_ws) {
  __shared__ char sm[LDSE];
  float* bl = (float*)(sm + 49152);
  int tid = threadIdx.x, lane = tid & 63;
  int r15 = lane & 15, hi = lane >> 4;
  int wbase = (tid >> 6) * 32;
  h8 B0[8], B1[8], B2[8], B3[8], B4[8];
  loadW(B1, wt + WT_ENCW + 16384,   wbase, r15, hi);
  loadW(B2, wt + WT_ENCW + 2*16384, wbase, r15, hi);
  loadW(B3, wt + WT_ENCW + 3*16384, wbase, r15, hi);
  loadW(B4, wt + WT_ENCWOUT,        wbase, r15, hi);
  bl[tid] = enc_b[tid]; bl[256 + tid] = enc_b[256 + tid];
  if (tid < 128) bl[512 + tid] = enc_bout[tid];
  f4 acc[4][2];

  for (int t = blockIdx.x; t < NT64; t += gridDim.x) {
    loadW(B0, wt + WT_ENCW, wbase, r15, hi);      // L0 (comb rotates into B0)
    size_t rb = (size_t)t * 64;
#pragma unroll
    for (int i = 0; i < 4; ++i) {                 // stage x -> h0 (enc skip)
      int idx = i*256 + tid, rl = idx >> 4, c = idx & 15;
      const float* s = x + (rb + rl)*128 + c*8;
      f4 v0 = *(const f4*)s, v1 = *(const f4*)(s + 4);
      *(h8*)(sm + H0 + hsw(rl, c)) = cvt8(v0, v1);
    }
    __syncthreads();
    mmF4s(sm, H0, B0, acc, r15, hi);
    loadW(B0, wt + WT_COMB, wbase, r15, hi);      // rotate B0 -> comb
    hw4s(sm, H1, wbase, acc, bl, 0,   r15, hi); __syncthreads();
    mmF4s(sm, H1, B1, acc, r15, hi); hw4s(sm, H2, wbase, acc, bl, 128, r15, hi); __syncthreads();
    mmF4s(sm, H2, B2, acc, r15, hi); hw4s(sm, H1, wbase, acc, bl, 256, r15, hi); __syncthreads();
    mmF4s(sm, H1, B3, acc, r15, hi); hw4s(sm, H2, wbase, acc, bl, 384, r15, hi); __syncthreads();
    mmF4s(sm, H2, B4, acc, r15, hi);              // encWout
    // pe = acc + bout + x(h0 b64) -> H1 b64
    {
      f4 bb0 = *(const f4*)(bl + 512 + wbase + hi*4);
      f4 bb1 = *(const f4*)(bl + 512 + wbase + 16 + hi*4);
      int bo2 = (hi & 1) * 8;
#pragma unroll
      for (int nt = 0; nt < 2; ++nt) {
        int c = ((wbase + nt*16) >> 3) + (hi >> 1);
        f4 bb = nt ? bb1 : bb0;
#pragma unroll
        for (int rt = 0; rt < 4; ++rt) {
          int row = rt*16 + r15;
          int soff = row*256 + ((c ^ (row & 7)) << 4) + bo2;
          h4 sk = *(const h4*)(sm + H0 + soff);
          h4 p;
#pragma unroll
          for (int d = 0; d < 4; ++d) p[d] = (_Float16)(acc[rt][nt][d] + bb[d] + (float)sk[d]);
          *(h4*)(sm + H1 + soff) = p;
        }
      }
    }
    __syncthreads();
    {                                             // dump pe image (plain full-line)
      char* g = (char*)(pe_ws) + (size_t)t*16384;
#pragma unroll
      for (int i = 0; i < 4; ++i) { int off = (i*256 + tid)*16;
        *(f4*)(g + off) = *(const f4*)(sm + H1 + off); }
    }
    mmF4s(sm, H1, B0, acc, r15, hi);              // pd = pe @ comb
    {
      int bo2 = (hi & 1) * 8;
#pragma unroll
      for (int nt = 0; nt < 2; ++nt) {
        int c = ((wbase + nt*16) >> 3) + (hi >> 1);
#pragma unroll
        for (int rt = 0; rt < 4; ++rt) {
          int row = rt*16 + r15;
          h4 p;
#pragma unroll
          for (int d = 0; d < 4; ++d) p[d] = (_Float16)acc[rt][nt][d];
          *(h4*)(sm + H2 + row*256 + ((c ^ (row & 7)) << 4) + bo2) = p;
        }
      }
    }
    __syncthreads();
    {                                             // dump pd image
      char* g = (char*)(pd_ws) + (size_t)t*16384;
#pragma unroll
      for (int i = 0; i < 4; ++i) { int off = (i*256 + tid)*16;
        *(f4*)(g + off) = *(const f4*)(sm + H2 + off); }
    }
  }
}

// ---------------- decoder: pe_ws -> out2, pd_ws -> out1 ----------------

__global__ __launch_bounds__(256, 3) void k_dec(
    const _Float16* __restrict__ wt, const _Float16* __restrict__ pe_ws,
    const _Float16* __restrict__ pd_ws,
    const float* __restrict__ dec_b, const float* __restrict__ dec_bout,
    float* __restrict__ out1, float* __restrict__ out2) {
  __shared__ char sm[LDSE];
  float* bl = (float*)(sm + 49152);
  int tid = threadIdx.x, lane = tid & 63;
  int r15 = lane & 15, hi = lane >> 4;
  int wbase = (tid >> 6) * 32;
  h8 B0[8], B1[8], B2[8], B3[8], B4[8];
  loadW(B0, wt + WT_DECW,           wbase, r15, hi);
  loadW(B1, wt + WT_DECW + 16384,   wbase, r15, hi);
  loadW(B2, wt + WT_DECW + 2*16384, wbase, r15, hi);
  loadW(B3, wt + WT_DECW + 3*16384, wbase, r15, hi);
  loadW(B4, wt + WT_DECWOUT,        wbase, r15, hi);
  bl[tid] = dec_b[tid]; bl[256 + tid] = dec_b[256 + tid];
  if (tid < 128) bl[512 + tid] = dec_bout[tid];
  f4 acc[4][2];

  for (int u = blockIdx.x; u < 2*NT64; u += gridDim.x) {
    int t = (u >= NT64) ? u - NT64 : u;
    const char* src = (const char*)((u >= NT64) ? pd_ws : pe_ws) + (size_t)t*16384;
    float* dst = ((u >= NT64) ? out1 : out2) + (size_t)t*64*128;
#pragma unroll
    for (int i = 0; i < 4; ++i) {                 // stage input image -> h0 (= skip)
      int off = (i*256 + tid)*16;
      *(f4*)(sm + H0 + off) = *(const f4*)(src + off);
    }
    __syncthreads();
    mmF4s(sm, H0, B0, acc, r15, hi); hw4s(sm, H1, wbase, acc, bl, 0,   r15, hi); __syncthreads();
    mmF4s(sm, H1, B1, acc, r15, hi); hw4s(sm, H2, wbase, acc, bl, 128, r15, hi); __syncthreads();
    mmF4s(sm, H2, B2, acc, r15, hi); hw4s(sm, H1, wbase, acc, bl, 256, r15, hi); __syncthreads();
    mmF4s(sm, H1, B3, acc, r15, hi); hw4s(sm, H2, wbase, acc, bl, 384, r15, hi); __syncthreads();
    mmF4s(sm, H2, B4, acc, r15, hi);              // decWout
    __syncthreads();                              // H2 reads done (trbuf = H1+H2)
    {                                             // out = acc + bout + skip -> trbuf b128
      f4 bb0 = *(const f4*)(bl + 512 + wbase + hi*4);
      f4 bb1 = *(const f4*)(bl + 512 + wbase + 16 + hi*4);
      int bo2 = (hi & 1) * 8;
#pragma unroll
      for (int nt = 0; nt < 2; ++nt) {
        int c = ((wbase + nt*16) >> 3) + (hi >> 1);
        int q = (wbase >> 2) + nt*4 + hi;
        f4 bb = nt ? bb1 : bb0;
#pragma unroll
        for (int rt = 0; rt < 4; ++rt) {
          int row = rt*16 + r15;
          h4 sk = *(const h4*)(sm + H0 + row*256 + ((c ^ (row & 7)) << 4) + bo2);
          f4 v;
#pragma unroll
          for (int d = 0; d < 4; ++d) v[d] = acc[rt][nt][d] + bb[d] + (float)sk[d];
          *(f4*)(sm + H1 + row*512 + ((q ^ ((row & 7) << 2)) << 4)) = v;
        }
      }
    }
    __syncthreads();
    {                                             // flat full-line PLAIN stores
#pragma unroll
      for (int i = 0; i < 8; ++i) {
        int idx = i*256 + tid, row = idx >> 5, q = idx & 31;
        f4 v = *(const f4*)(sm + H1 + row*512 + ((q ^ ((row & 7) << 2)) << 4));
        *(f4*)(dst + (size_t)row*128 + q*4) = v;
      }
    }
  }
}

// ---------------- prediction: pe(t=0) @ Mfull_s -> dec -> out3 ----------------

__global__ __launch_bounds__(256, 4) void k_pred(
    const _Float16* __restrict__ pe_ws, const _Float16* __restrict__ wt,
    const _Float16* __restrict__ mfull,
    const float* __restrict__ dec_b, const float* __restrict__ dec_bout,
    float* __restrict__ out3) {
  __shared__ char sm[LDSP];
  float* bl = (float*)(sm + 32768);
  int tid = threadIdx.x, lane = tid & 63;
  int r15 = lane & 15, hi = lane >> 4;
  int wbase = (tid >> 6) * 32;
  h8 B0[8], B1[8], B2[8], B3[8], B4[8], Bm[8];
  loadW(B0, wt + WT_DECW,           wbase, r15, hi);
  loadW(B1, wt + WT_DECW + 16384,   wbase, r15, hi);
  loadW(B2, wt + WT_DECW + 2*16384, wbase, r15, hi);
  loadW(B3, wt + WT_DECW + 3*16384, wbase, r15, hi);
  loadW(B4, wt + WT_DECWOUT,        wbase, r15, hi);
  bl[tid] = dec_b[tid]; bl[256 + tid] = dec_b[256 + tid];
  if (tid < 128) bl[512 + tid] = dec_bout[tid];
  f4 acc[2][2];

  int rtile = blockIdx.x / 10, chunk = blockIdx.x % 10;  // 64 x 10 grid
#pragma unroll
  for (int i = 0; i < 2; ++i) {                   // stage pe t=0 rows -> hp (once)
    int idx = i*256 + tid, rl = idx >> 4, c = idx & 15;
    int rg = rtile*32 + rl;
    int r  = rg * 51;                             // pe row of t=0 sample rg
    const char* sp = (const char*)pe_ws + (size_t)(r >> 6)*16384
                   + (r & 63)*256 + ((c ^ ((r & 63) & 7)) << 4);
    *(f4*)(sm + HP + hsw(rl, c)) = *(const f4*)sp;
  }
  __syncthreads();

  for (int s = chunk*5; s < chunk*5 + 5; ++s) {
    loadW(Bm, mfull + (size_t)s*16384, wbase, r15, hi);
    mmF2s(sm, HP, Bm, acc, r15, hi);              // di = pe_t0 @ Mfull_s
    {                                             // di -> P0 b64 (input + skip)
      int bo2 = (hi & 1) * 8;
#pragma unroll
      for (int nt = 0; nt < 2; ++nt) {
        int c = ((wbase + nt*16) >> 3) + (hi >> 1);
#pragma unroll
        for (int rt = 0; rt < 2; ++rt) {
          int row = rt*16 + r15;
          h4 p;
#pragma unroll
          for (int d = 0; d < 4; ++d) p[d] = (_Float16)acc[rt][nt][d];
          *(h4*)(sm + P0 + row*256 + ((c ^ (row & 7)) << 4) + bo2) = p;
        }
      }
    }
    __syncthreads();
    mmF2s(sm, P0, B0, acc, r15, hi); hw2s(sm, P1, wbase, acc, bl, 0,   r15, hi); __syncthreads();
    mmF2s(sm, P1, B1, acc, r15, hi); hw2s(sm, P2, wbase, acc, bl, 128, r15, hi); __syncthreads();
    mmF2s(sm, P2, B2, acc, r15, hi); hw2s(sm, P1, wbase, acc, bl, 256, r15, hi); __syncthreads();
    mmF2s(sm, P1, B3, acc, r15, hi); hw2s(sm, P2, wbase, acc, bl, 384, r15, hi); __syncthreads();
    mmF2s(sm, P2, B4, acc, r15, hi);              // decWout
    __syncthreads();                              // P2 reads done (trbuf = P1+P2)
    {
      f4 bb0 = *(const f4*)(bl + 512 + wbase + hi*4);
      f4 bb1 = *(const f4*)(bl + 512 + wbase + 16 + hi*4);
      int bo2 = (hi & 1) * 8;
#pragma unroll
      for (int nt = 0; nt < 2; ++nt) {
        int c = ((wbase + nt*16) >> 3) + (hi >> 1);
        int q = (wbase >> 2) + nt*4 + hi;
        f4 bb = nt ? bb1 : bb0;
#pragma unroll
        for (int rt = 0; rt < 2; ++rt) {
          int row = rt*16 + r15;
          h4 sk = *(const h4*)(sm + P0 + row*256 + ((c ^ (row & 7)) << 4) + bo2);
          f4 v;
#pragma unroll
          for (int d = 0; d < 4; ++d) v[d] = acc[rt][nt][d] + bb[d] + (float)sk[d];
          *(f4*)(sm + P1 + row*512 + ((q ^ ((row & 7) << 2)) << 4)) = v;
        }
      }
    }
    __syncthreads();
    {                                             // flat full-line PLAIN stores
#pragma unroll
      for (int i = 0; i < 4; ++i) {
        int idx = i*256 + tid, row = idx >> 5, q = idx & 31;
        size_t b = (size_t)(rtile*32 + row);
        f4 v = *(const f4*)(sm + P1 + row*512 + ((q ^ ((row & 7) << 2)) << 4));
        *(f4*)(out3 + (b*50 + s)*128 + q*4) = v;
      }
    }
    __syncthreads();
  }
}

// ---------------- launch ----------------

extern "C" void kernel_launch(void* const* d_in, const int* in_sizes, int n_in,
                              void* d_out, int out_size, void* d_ws, size_t ws_size,
                              hipStream_t stream) {
  const float* x        = (const float*)d_in[0];
  const float* encW     = (const float*)d_in[1];
  const float* enc_b    = (const float*)d_in[2];
  const float* encWout  = (const float*)d_in[3];
  const float* enc_bout = (const float*)d_in[4];
  const float* decW     = (const float*)d_in[5];
  const float* dec_b    = (const float*)d_in[6];
  const float* decWout  = (const float*)d_in[7];
  const float* dec_bout = (const float*)d_in[8];
  const float* wencI    = (const float*)d_in[9];
  const float* L        = (const float*)d_in[10];
  const float* wdecI    = (const float*)d_in[11];

  char* ws = (char*)d_ws;
  _Float16* wt    = (_Float16*)ws;
  _Float16* mfull = (_Float16*)(ws + MFULL_OFF_B);
  float*    ach   = (float*)(ws + ACH_OFF_B);
  _Float16* pe_ws = (_Float16*)(ws + PE_OFF_B);
  _Float16* pd_ws = (_Float16*)(ws + PD_OFF_B);

  float* out1 = (float*)d_out;                       // autoencoder_output
  float* out2 = out1 + (size_t)ROWS_AUTO*128;        // outer_auto_output
  float* out3 = out2 + (size_t)ROWS_AUTO*128;        // predictions [2048][50][128]

  hipLaunchKernelGGL(k_prep, dim3(32, 11), dim3(512), 0, stream,
                     encW, encWout, decW, decWout, L, wt, ach);
  hipLaunchKernelGGL(k_aux, dim3(51), dim3(512), 0, stream,
                     ach, wencI, wdecI, mfull, wt);
  hipLaunchKernelGGL(k_enc, dim3(768), dim3(256), 0, stream,
                     x, wt, enc_b, enc_bout, pe_ws, pd_ws);
  hipLaunchKernelGGL(k_pred, dim3(640), dim3(256), 0, stream,
                     pe_ws, wt, mfull, dec_b, dec_bout, out3);
  hipLaunchKernelGGL(k_dec, dim3(768), dim3(256), 0, stream,
                     wt, pe_ws, pd_ws, dec_b, dec_bout, out1, out2);
}

// Round 8
// 232.928 us; speedup vs baseline: 2.0075x; 1.5253x over previous
//
#include <hip/hip_runtime.h>
#include <stdint.h>

// Koopman autoencoder — round 8 (MI355X / gfx950).
// R7 + weight REGISTER PINNING: asm-opaque fragments stop the compiler from
// sinking weight loads into the tile loop (R7: VGPR=84 -> per-tile L2/HBM
// weight re-fetch, 135MB excess FETCH). launch_bounds (256,2), grids=512.

typedef _Float16 h8 __attribute__((ext_vector_type(8)));
typedef _Float16 h4 __attribute__((ext_vector_type(4)));
typedef float    f4 __attribute__((ext_vector_type(4)));

#define ROWS_AUTO 104448
#define NT64      1632           // 64-row tiles

// half-element offsets inside wt (all mats stored as W^T [n][k])
#define WT_ENCW      0
#define WT_ENCWOUT   (4*16384)
#define WT_DECW      (5*16384)
#define WT_DECWOUT   (9*16384)
#define WT_COMB      (10*16384)  // (WencI@WdecI)^T [128][128]

// ws byte offsets
#define MFULL_OFF_B 0x60000      // f16 [50][128][128] (WencI@L^{s+1}@WdecI)^T
#define ACH_OFF_B   0x200000     // f32 [50][441]
#define PE_OFF_B    0x220000     // f16 LDS-image tiles [1632][16384B]
#define PD_OFF_B    0x1C00000    // f16 LDS-image tiles [1632][16384B]

// k_enc/k_dec LDS: h0 h1 h2 (16KB each) + biases
#define H0 0
#define H1 16384
#define H2 32768
#define LDSE 51712
// k_pred LDS: hp p0 p1 p2 (16KB each) + biases
#define HP 0
#define P0 16384
#define P1 32768
#define P2 49152
#define LDSP 68096

#define hsw(rl, c) ((rl)*256 + ((((c)) ^ ((rl) & 7)) << 4))

// opaque pin: forbids rematerialization of the weight loads
#define PIN(B) asm volatile("" : "+v"(B[0]), "+v"(B[1]), "+v"(B[2]), "+v"(B[3]), \
                                 "+v"(B[4]), "+v"(B[5]), "+v"(B[6]), "+v"(B[7]))

__device__ __forceinline__ f4 mfma16(h8 a, h8 b, f4 c) {
  return __builtin_amdgcn_mfma_f32_16x16x32_f16(a, b, c, 0, 0, 0);
}
__device__ __forceinline__ h8 cvt8(f4 a, f4 b) {
  h8 r;
  r[0]=(_Float16)a[0]; r[1]=(_Float16)a[1]; r[2]=(_Float16)a[2]; r[3]=(_Float16)a[3];
  r[4]=(_Float16)b[0]; r[5]=(_Float16)b[1]; r[6]=(_Float16)b[2]; r[7]=(_Float16)b[3];
  return r;
}
// wave's 32-col slice of a 128x128 W^T
__device__ __forceinline__ void loadW(h8 B[8], const _Float16* gW, int nbase, int r15, int hi) {
#pragma unroll
  for (int nt = 0; nt < 2; ++nt)
#pragma unroll
    for (int ks = 0; ks < 4; ++ks)
      B[nt*4+ks] = *(const h8*)(gW + (size_t)(nbase + nt*16 + r15)*128 + ks*32 + hi*8);
}

// SWAPPED: lane holds out[row=rt*16+r15][n=wbase+nt*16+hi*4+d]
__device__ __forceinline__ void mmF4s(const char* sm, int hb, const h8 B[8],
                                      f4 acc[4][2], int r15, int hi) {
#pragma unroll
  for (int rt = 0; rt < 4; ++rt) { acc[rt][0] = (f4){0,0,0,0}; acc[rt][1] = (f4){0,0,0,0}; }
#pragma unroll
  for (int ks = 0; ks < 4; ++ks) {
    int c = ks*4 + hi;
    h8 a[4];
#pragma unroll
    for (int rt = 0; rt < 4; ++rt) a[rt] = *(const h8*)(sm + hb + hsw(rt*16 + r15, c));
#pragma unroll
    for (int rt = 0; rt < 4; ++rt) {
      acc[rt][0] = mfma16(B[ks],   a[rt], acc[rt][0]);
      acc[rt][1] = mfma16(B[4+ks], a[rt], acc[rt][1]);
    }
  }
}

// ReLU(acc + bias) -> h[hb] via b64 writes
__device__ __forceinline__ void hw4s(char* sm, int hb, int wbase, const f4 acc[4][2],
                                     const float* bl, int bo, int r15, int hi) {
  f4 bb0 = *(const f4*)(bl + bo + wbase + hi*4);
  f4 bb1 = *(const f4*)(bl + bo + wbase + 16 + hi*4);
  int bo2 = (hi & 1) * 8;
#pragma unroll
  for (int nt = 0; nt < 2; ++nt) {
    int c = ((wbase + nt*16) >> 3) + (hi >> 1);
    f4 bb = nt ? bb1 : bb0;
#pragma unroll
    for (int rt = 0; rt < 4; ++rt) {
      int row = rt*16 + r15;
      h4 p;
#pragma unroll
      for (int d = 0; d < 4; ++d) p[d] = (_Float16)fmaxf(acc[rt][nt][d] + bb[d], 0.f);
      *(h4*)(sm + hb + row*256 + ((c ^ (row & 7)) << 4) + bo2) = p;
    }
  }
}
// raw acc -> h[hb] (no bias/relu)
__device__ __forceinline__ void hw4r(char* sm, int hb, int wbase, const f4 acc[4][2],
                                     int r15, int hi) {
  int bo2 = (hi & 1) * 8;
#pragma unroll
  for (int nt = 0; nt < 2; ++nt) {
    int c = ((wbase + nt*16) >> 3) + (hi >> 1);
#pragma unroll
    for (int rt = 0; rt < 4; ++rt) {
      int row = rt*16 + r15;
      h4 p;
#pragma unroll
      for (int d = 0; d < 4; ++d) p[d] = (_Float16)acc[rt][nt][d];
      *(h4*)(sm + hb + row*256 + ((c ^ (row & 7)) << 4) + bo2) = p;
    }
  }
}

// ---------------- prep kernels ----------------

__global__ __launch_bounds__(512) void k_prep(
    const float* __restrict__ encW, const float* __restrict__ encWout,
    const float* __restrict__ decW, const float* __restrict__ decWout,
    const float* __restrict__ L,
    _Float16* __restrict__ wt, float* __restrict__ ach) {
  __shared__ float chA[441], chB[441];
  int m = blockIdx.y, tid = threadIdx.x;
  if (m == 10) {                                  // serial L-power chain
    if (blockIdx.x != 0) return;
    if (tid < 441) chA[tid] = L[tid];
    __syncthreads();
    for (int s = 0; s < 50; ++s) {
      if (tid < 441) ach[s*441 + tid] = chA[tid];
      if (s == 49) break;
      if (tid < 441) {
        int i = tid / 21, j = tid % 21; float a = 0.f;
        for (int k = 0; k < 21; ++k) a += chA[i*21 + k] * L[k*21 + j];
        chB[tid] = a;
      }
      __syncthreads();
      if (tid < 441) chA[tid] = chB[tid];
      __syncthreads();
    }
    return;
  }
  int idx = blockIdx.x*512 + tid;
  if (idx >= 16384) return;
  const float* src; _Float16* dst;
  if (m < 4)       { src = encW + m*16384;     dst = wt + WT_ENCW + m*16384; }
  else if (m == 4) { src = encWout;            dst = wt + WT_ENCWOUT; }
  else if (m < 9)  { src = decW + (m-5)*16384; dst = wt + WT_DECW + (m-5)*16384; }
  else             { src = decWout;            dst = wt + WT_DECWOUT; }
  int n = idx >> 7, k = idx & 127;
  dst[idx] = (_Float16)src[k*128 + n];            // W^T[n][k]
}

// block s<50: Mfull_s = WencI @ L^{s+1} @ WdecI ; s==50: Wcomb
__global__ __launch_bounds__(512) void k_aux(
    const float* __restrict__ ach, const float* __restrict__ wencI,
    const float* __restrict__ wdecI,
    _Float16* __restrict__ mfull, _Float16* __restrict__ wt) {
  __shared__ float T1[2688];
  __shared__ float sa[441];
  int s = blockIdx.x, t = threadIdx.x;
  if (s < 50) {
    if (t < 441) sa[t] = ach[s*441 + t];
    __syncthreads();
    for (int idx = t; idx < 2688; idx += 512) {
      int k = idx / 21, j = idx % 21;
      float a = 0.f;
      for (int u = 0; u < 21; ++u) a += wencI[k*21 + u] * sa[u*21 + j];
      T1[idx] = a;
    }
  } else {
    for (int idx = t; idx < 2688; idx += 512) T1[idx] = wencI[idx];
  }
  __syncthreads();
  _Float16* dst = (s < 50) ? (mfull + (size_t)s*16384) : (wt + WT_COMB);
  for (int idx = t; idx < 16384; idx += 512) {    // M^T[n][k]
    int n = idx >> 7, k = idx & 127;
    float a = 0.f;
    for (int j = 0; j < 21; ++j) a += T1[k*21 + j] * wdecI[j*128 + n];
    dst[idx] = (_Float16)a;
  }
}

// ---------------- encoder: x -> pe_ws, pd_ws (f16 LDS-images) ----------------

__global__ __launch_bounds__(256, 2) void k_enc(
    const float* __restrict__ x, const _Float16* __restrict__ wt,
    const float* __restrict__ enc_b, const float* __restrict__ enc_bout,
    _Float16* __restrict__ pe_ws, _Float16* __restrict__ pd_ws) {
  __shared__ char sm[LDSE];
  float* bl = (float*)(sm + 49152);
  int tid = threadIdx.x, lane = tid & 63;
  int r15 = lane & 15, hi = lane >> 4;
  int wbase = (tid >> 6) * 32;
  h8 B0[8], B1[8], B2[8], B3[8], B4[8], B5[8];
  loadW(B0, wt + WT_ENCW,           wbase, r15, hi);
  loadW(B1, wt + WT_ENCW + 16384,   wbase, r15, hi);
  loadW(B2, wt + WT_ENCW + 2*16384, wbase, r15, hi);
  loadW(B3, wt + WT_ENCW + 3*16384, wbase, r15, hi);
  loadW(B4, wt + WT_ENCWOUT,        wbase, r15, hi);
  loadW(B5, wt + WT_COMB,           wbase, r15, hi);
  PIN(B0); PIN(B1); PIN(B2); PIN(B3); PIN(B4); PIN(B5);
  bl[tid] = enc_b[tid]; bl[256 + tid] = enc_b[256 + tid];
  if (tid < 128) bl[512 + tid] = enc_bout[tid];
  f4 acc[4][2];

  for (int t = blockIdx.x; t < NT64; t += gridDim.x) {
    size_t rb = (size_t)t * 64;
#pragma unroll
    for (int i = 0; i < 4; ++i) {                 // stage x -> h0 (enc skip)
      int idx = i*256 + tid, rl = idx >> 4, c = idx & 15;
      const float* s = x + (rb + rl)*128 + c*8;
      f4 v0 = *(const f4*)s, v1 = *(const f4*)(s + 4);
      *(h8*)(sm + H0 + hsw(rl, c)) = cvt8(v0, v1);
    }
    __syncthreads();
    mmF4s(sm, H0, B0, acc, r15, hi); hw4s(sm, H1, wbase, acc, bl, 0,   r15, hi); __syncthreads();
    mmF4s(sm, H1, B1, acc, r15, hi); hw4s(sm, H2, wbase, acc, bl, 128, r15, hi); __syncthreads();
    mmF4s(sm, H2, B2, acc, r15, hi); hw4s(sm, H1, wbase, acc, bl, 256, r15, hi); __syncthreads();
    mmF4s(sm, H1, B3, acc, r15, hi); hw4s(sm, H2, wbase, acc, bl, 384, r15, hi); __syncthreads();
    mmF4s(sm, H2, B4, acc, r15, hi);              // encWout
    // pe = acc + bout + x(h0) -> H1 b64
    {
      f4 bb0 = *(const f4*)(bl + 512 + wbase + hi*4);
      f4 bb1 = *(const f4*)(bl + 512 + wbase + 16 + hi*4);
      int bo2 = (hi & 1) * 8;
#pragma unroll
      for (int nt = 0; nt < 2; ++nt) {
        int c = ((wbase + nt*16) >> 3) + (hi >> 1);
        f4 bb = nt ? bb1 : bb0;
#pragma unroll
        for (int rt = 0; rt < 4; ++rt) {
          int row = rt*16 + r15;
          int soff = row*256 + ((c ^ (row & 7)) << 4) + bo2;
          h4 sk = *(const h4*)(sm + H0 + soff);
          h4 p;
#pragma unroll
          for (int d = 0; d < 4; ++d) p[d] = (_Float16)(acc[rt][nt][d] + bb[d] + (float)sk[d]);
          *(h4*)(sm + H1 + soff) = p;
        }
      }
    }
    __syncthreads();
    {                                             // dump pe image
      char* g = (char*)(pe_ws) + (size_t)t*16384;
#pragma unroll
      for (int i = 0; i < 4; ++i) { int off = (i*256 + tid)*16;
        *(f4*)(g + off) = *(const f4*)(sm + H1 + off); }
    }
    mmF4s(sm, H1, B5, acc, r15, hi);              // pd = pe @ comb
    hw4r(sm, H2, wbase, acc, r15, hi);
    __syncthreads();
    {                                             // dump pd image
      char* g = (char*)(pd_ws) + (size_t)t*16384;
#pragma unroll
      for (int i = 0; i < 4; ++i) { int off = (i*256 + tid)*16;
        *(f4*)(g + off) = *(const f4*)(sm + H2 + off); }
    }
  }
}

// ---------------- decoder: pe_ws -> out2, pd_ws -> out1 ----------------

__global__ __launch_bounds__(256, 2) void k_dec(
    const _Float16* __restrict__ wt, const _Float16* __restrict__ pe_ws,
    const _Float16* __restrict__ pd_ws,
    const float* __restrict__ dec_b, const float* __restrict__ dec_bout,
    float* __restrict__ out1, float* __restrict__ out2) {
  __shared__ char sm[LDSE];
  float* bl = (float*)(sm + 49152);
  int tid = threadIdx.x, lane = tid & 63;
  int r15 = lane & 15, hi = lane >> 4;
  int wbase = (tid >> 6) * 32;
  h8 B0[8], B1[8], B2[8], B3[8], B4[8];
  loadW(B0, wt + WT_DECW,           wbase, r15, hi);
  loadW(B1, wt + WT_DECW + 16384,   wbase, r15, hi);
  loadW(B2, wt + WT_DECW + 2*16384, wbase, r15, hi);
  loadW(B3, wt + WT_DECW + 3*16384, wbase, r15, hi);
  loadW(B4, wt + WT_DECWOUT,        wbase, r15, hi);
  PIN(B0); PIN(B1); PIN(B2); PIN(B3); PIN(B4);
  bl[tid] = dec_b[tid]; bl[256 + tid] = dec_b[256 + tid];
  if (tid < 128) bl[512 + tid] = dec_bout[tid];
  f4 acc[4][2];

  for (int u = blockIdx.x; u < 2*NT64; u += gridDim.x) {
    int t = (u >= NT64) ? u - NT64 : u;
    const char* src = (const char*)((u >= NT64) ? pd_ws : pe_ws) + (size_t)t*16384;
    float* dst = ((u >= NT64) ? out1 : out2) + (size_t)t*64*128;
#pragma unroll
    for (int i = 0; i < 4; ++i) {                 // stage input image -> h0 (= skip)
      int off = (i*256 + tid)*16;
      *(f4*)(sm + H0 + off) = *(const f4*)(src + off);
    }
    __syncthreads();
    mmF4s(sm, H0, B0, acc, r15, hi); hw4s(sm, H1, wbase, acc, bl, 0,   r15, hi); __syncthreads();
    mmF4s(sm, H1, B1, acc, r15, hi); hw4s(sm, H2, wbase, acc, bl, 128, r15, hi); __syncthreads();
    mmF4s(sm, H2, B2, acc, r15, hi); hw4s(sm, H1, wbase, acc, bl, 256, r15, hi); __syncthreads();
    mmF4s(sm, H1, B3, acc, r15, hi); hw4s(sm, H2, wbase, acc, bl, 384, r15, hi); __syncthreads();
    mmF4s(sm, H2, B4, acc, r15, hi);              // decWout
    __syncthreads();                              // H2 reads done (trbuf = H1+H2)
    {                                             // out = acc + bout + skip -> trbuf b128
      f4 bb0 = *(const f4*)(bl + 512 + wbase + hi*4);
      f4 bb1 = *(const f4*)(bl + 512 + wbase + 16 + hi*4);
      int bo2 = (hi & 1) * 8;
#pragma unroll
      for (int nt = 0; nt < 2; ++nt) {
        int c = ((wbase + nt*16) >> 3) + (hi >> 1);
        int q = (wbase >> 2) + nt*4 + hi;
        f4 bb = nt ? bb1 : bb0;
#pragma unroll
        for (int rt = 0; rt < 4; ++rt) {
          int row = rt*16 + r15;
          h4 sk = *(const h4*)(sm + H0 + row*256 + ((c ^ (row & 7)) << 4) + bo2);
          f4 v;
#pragma unroll
          for (int d = 0; d < 4; ++d) v[d] = acc[rt][nt][d] + bb[d] + (float)sk[d];
          *(f4*)(sm + H1 + row*512 + ((q ^ ((row & 7) << 2)) << 4)) = v;
        }
      }
    }
    __syncthreads();
    {                                             // flat full-line stores
#pragma unroll
      for (int i = 0; i < 8; ++i) {
        int idx = i*256 + tid, row = idx >> 5, q = idx & 31;
        f4 v = *(const f4*)(sm + H1 + row*512 + ((q ^ ((row & 7) << 2)) << 4));
        *(f4*)(dst + (size_t)row*128 + q*4) = v;
      }
    }
  }
}

// ---------------- prediction: pe(t=0) @ Mfull_s -> dec -> out3 ----------------

__global__ __launch_bounds__(256, 2) void k_pred(
    const _Float16* __restrict__ pe_ws, const _Float16* __restrict__ wt,
    const _Float16* __restrict__ mfull,
    const float* __restrict__ dec_b, const float* __restrict__ dec_bout,
    float* __restrict__ out3) {
  __shared__ char sm[LDSP];
  float* bl = (float*)(sm + 65536);
  int tid = threadIdx.x, lane = tid & 63;
  int r15 = lane & 15, hi = lane >> 4;
  int wbase = (tid >> 6) * 32;
  h8 B0[8], B1[8], B2[8], B3[8], B4[8];
  loadW(B0, wt + WT_DECW,           wbase, r15, hi);
  loadW(B1, wt + WT_DECW + 16384,   wbase, r15, hi);
  loadW(B2, wt + WT_DECW + 2*16384, wbase, r15, hi);
  loadW(B3, wt + WT_DECW + 3*16384, wbase, r15, hi);
  loadW(B4, wt + WT_DECWOUT,        wbase, r15, hi);
  PIN(B0); PIN(B1); PIN(B2); PIN(B3); PIN(B4);
  bl[tid] = dec_b[tid]; bl[256 + tid] = dec_b[256 + tid];
  if (tid < 128) bl[512 + tid] = dec_bout[tid];
  f4 acc[4][2];

  int rtile = blockIdx.x / 10, chunk = blockIdx.x % 10;  // 32 x 10 grid, 64 rows/block
#pragma unroll
  for (int i = 0; i < 4; ++i) {                   // stage pe t=0 rows -> HP (once)
    int idx = i*256 + tid, rl = idx >> 4, c = idx & 15;
    int rg = rtile*64 + rl;
    int r  = rg * 51;                             // pe row of t=0 sample rg
    const char* sp = (const char*)pe_ws + (size_t)(r >> 6)*16384
                   + (r & 63)*256 + ((c ^ ((r & 63) & 7)) << 4);
    *(f4*)(sm + HP + hsw(rl, c)) = *(const f4*)sp;
  }
  __syncthreads();

  for (int s = chunk*5; s < chunk*5 + 5; ++s) {
    h8 Bm[8];
    loadW(Bm, mfull + (size_t)s*16384, wbase, r15, hi);
    mmF4s(sm, HP, Bm, acc, r15, hi);              // di = pe_t0 @ Mfull_s
    hw4r(sm, P0, wbase, acc, r15, hi);            // di -> P0 (input + skip)
    __syncthreads();
    mmF4s(sm, P0, B0, acc, r15, hi); hw4s(sm, P1, wbase, acc, bl, 0,   r15, hi); __syncthreads();
    mmF4s(sm, P1, B1, acc, r15, hi); hw4s(sm, P2, wbase, acc, bl, 128, r15, hi); __syncthreads();
    mmF4s(sm, P2, B2, acc, r15, hi); hw4s(sm, P1, wbase, acc, bl, 256, r15, hi); __syncthreads();
    mmF4s(sm, P1, B3, acc, r15, hi); hw4s(sm, P2, wbase, acc, bl, 384, r15, hi); __syncthreads();
    mmF4s(sm, P2, B4, acc, r15, hi);              // decWout
    __syncthreads();                              // P2 reads done (trbuf = P1+P2)
    {
      f4 bb0 = *(const f4*)(bl + 512 + wbase + hi*4);
      f4 bb1 = *(const f4*)(bl + 512 + wbase + 16 + hi*4);
      int bo2 = (hi & 1) * 8;
#pragma unroll
      for (int nt = 0; nt < 2; ++nt) {
        int c = ((wbase + nt*16) >> 3) + (hi >> 1);
        int q = (wbase >> 2) + nt*4 + hi;
        f4 bb = nt ? bb1 : bb0;
#pragma unroll
        for (int rt = 0; rt < 4; ++rt) {
          int row = rt*16 + r15;
          h4 sk = *(const h4*)(sm + P0 + row*256 + ((c ^ (row & 7)) << 4) + bo2);
          f4 v;
#pragma unroll
          for (int d = 0; d < 4; ++d) v[d] = acc[rt][nt][d] + bb[d] + (float)sk[d];
          *(f4*)(sm + P1 + row*512 + ((q ^ ((row & 7) << 2)) << 4)) = v;
        }
      }
    }
    __syncthreads();
    {                                             // flat full-line stores
#pragma unroll
      for (int i = 0; i < 8; ++i) {
        int idx = i*256 + tid, row = idx >> 5, q = idx & 31;
        size_t b = (size_t)(rtile*64 + row);
        f4 v = *(const f4*)(sm + P1 + row*512 + ((q ^ ((row & 7) << 2)) << 4));
        *(f4*)(out3 + (b*50 + s)*128 + q*4) = v;
      }
    }
    __syncthreads();
  }
}

// ---------------- launch ----------------

extern "C" void kernel_launch(void* const* d_in, const int* in_sizes, int n_in,
                              void* d_out, int out_size, void* d_ws, size_t ws_size,
                              hipStream_t stream) {
  const float* x        = (const float*)d_in[0];
  const float* encW     = (const float*)d_in[1];
  const float* enc_b    = (const float*)d_in[2];
  const float* encWout  = (const float*)d_in[3];
  const float* enc_bout = (const float*)d_in[4];
  const float* decW     = (const float*)d_in[5];
  const float* dec_b    = (const float*)d_in[6];
  const float* decWout  = (const float*)d_in[7];
  const float* dec_bout = (const float*)d_in[8];
  const float* wencI    = (const float*)d_in[9];
  const float* L        = (const float*)d_in[10];
  const float* wdecI    = (const float*)d_in[11];

  char* ws = (char*)d_ws;
  _Float16* wt    = (_Float16*)ws;
  _Float16* mfull = (_Float16*)(ws + MFULL_OFF_B);
  float*    ach   = (float*)(ws + ACH_OFF_B);
  _Float16* pe_ws = (_Float16*)(ws + PE_OFF_B);
  _Float16* pd_ws = (_Float16*)(ws + PD_OFF_B);

  float* out1 = (float*)d_out;                       // autoencoder_output
  float* out2 = out1 + (size_t)ROWS_AUTO*128;        // outer_auto_output
  float* out3 = out2 + (size_t)ROWS_AUTO*128;        // predictions [2048][50][128]

  hipLaunchKernelGGL(k_prep, dim3(32, 11), dim3(512), 0, stream,
                     encW, encWout, decW, decWout, L, wt, ach);
  hipLaunchKernelGGL(k_aux, dim3(51), dim3(512), 0, stream,
                     ach, wencI, wdecI, mfull, wt);
  hipLaunchKernelGGL(k_enc, dim3(512), dim3(256), 0, stream,
                     x, wt, enc_b, enc_bout, pe_ws, pd_ws);
  hipLaunchKernelGGL(k_pred, dim3(320), dim3(256), 0, stream,
                     pe_ws, wt, mfull, dec_b, dec_bout, out3);
  hipLaunchKernelGGL(k_dec, dim3(512), dim3(256), 0, stream,
                     wt, pe_ws, pd_ws, dec_b, dec_bout, out1, out2);
}

// Round 9
// 224.649 us; speedup vs baseline: 2.0815x; 1.0369x over previous
//
#include <hip/hip_runtime.h>
#include <stdint.h>

// Koopman autoencoder — round 9 (MI355X / gfx950).
// Two main kernels: lean k_enc (5 pinned enc mats -> pe image + compact pet0),
// k_decpred (5 pinned dec mats; grid-stride over dec tiles + pred units).
// Dec tile reads pe once: out2=dec(pe), pd=pe@comb (transient comb), out1=dec(pd).

typedef _Float16 h8 __attribute__((ext_vector_type(8)));
typedef _Float16 h4 __attribute__((ext_vector_type(4)));
typedef float    f4 __attribute__((ext_vector_type(4)));

#define ROWS_AUTO 104448
#define NT64      1632           // 64-row dec tiles
#define NUNITS    1952           // 1632 dec + 320 pred

// half-element offsets inside wt (all mats stored as W^T [n][k])
#define WT_ENCW      0
#define WT_ENCWOUT   (4*16384)
#define WT_DECW      (5*16384)
#define WT_DECWOUT   (9*16384)
#define WT_COMB      (10*16384)  // (WencI@WdecI)^T [128][128]

// ws byte offsets
#define MFULL_OFF_B 0x60000      // f16 [50][128][128] (WencI@L^{s+1}@WdecI)^T
#define ACH_OFF_B   0x200000     // f32 [50][441]
#define PE_OFF_B    0x220000     // f16 LDS-image tiles [1632][16384B]
#define PET0_OFF_B  0x1C00000    // f16 [2048][128] compact pe at t=0 (chunk-linear)

// k_enc LDS: h0 h1 h2 (16KB) + biases
#define H0 0
#define H1 16384
#define H2 32768
#define H3 49152
#define LDSE 51712
#define LDSD 68096               // k_decpred: h0..h3 + biases

#define hsw(rl, c) ((rl)*256 + ((((c)) ^ ((rl) & 7)) << 4))

// opaque pin: forbids rematerialization/sinking of weight loads into the loop
#define PIN(B) asm volatile("" : "+v"(B[0]), "+v"(B[1]), "+v"(B[2]), "+v"(B[3]), \
                                 "+v"(B[4]), "+v"(B[5]), "+v"(B[6]), "+v"(B[7]))

__device__ __forceinline__ f4 mfma16(h8 a, h8 b, f4 c) {
  return __builtin_amdgcn_mfma_f32_16x16x32_f16(a, b, c, 0, 0, 0);
}
__device__ __forceinline__ h8 cvt8(f4 a, f4 b) {
  h8 r;
  r[0]=(_Float16)a[0]; r[1]=(_Float16)a[1]; r[2]=(_Float16)a[2]; r[3]=(_Float16)a[3];
  r[4]=(_Float16)b[0]; r[5]=(_Float16)b[1]; r[6]=(_Float16)b[2]; r[7]=(_Float16)b[3];
  return r;
}
// wave's 32-col slice of a 128x128 W^T
__device__ __forceinline__ void loadW(h8 B[8], const _Float16* gW, int nbase, int r15, int hi) {
#pragma unroll
  for (int nt = 0; nt < 2; ++nt)
#pragma unroll
    for (int ks = 0; ks < 4; ++ks)
      B[nt*4+ks] = *(const h8*)(gW + (size_t)(nbase + nt*16 + r15)*128 + ks*32 + hi*8);
}

// SWAPPED operands: lane holds out[row=rt*16+r15][n=wbase+nt*16+hi*4+d]
__device__ __forceinline__ void mmF4s(const char* sm, int hb, const h8 B[8],
                                      f4 acc[4][2], int r15, int hi) {
#pragma unroll
  for (int rt = 0; rt < 4; ++rt) { acc[rt][0] = (f4){0,0,0,0}; acc[rt][1] = (f4){0,0,0,0}; }
#pragma unroll
  for (int ks = 0; ks < 4; ++ks) {
    int c = ks*4 + hi;
    h8 a[4];
#pragma unroll
    for (int rt = 0; rt < 4; ++rt) a[rt] = *(const h8*)(sm + hb + hsw(rt*16 + r15, c));
#pragma unroll
    for (int rt = 0; rt < 4; ++rt) {
      acc[rt][0] = mfma16(B[ks],   a[rt], acc[rt][0]);
      acc[rt][1] = mfma16(B[4+ks], a[rt], acc[rt][1]);
    }
  }
}

// ReLU(acc + bias) -> h[hb] via b64 writes
__device__ __forceinline__ void hw4s(char* sm, int hb, int wbase, const f4 acc[4][2],
                                     const float* bl, int bo, int r15, int hi) {
  f4 bb0 = *(const f4*)(bl + bo + wbase + hi*4);
  f4 bb1 = *(const f4*)(bl + bo + wbase + 16 + hi*4);
  int bo2 = (hi & 1) * 8;
#pragma unroll
  for (int nt = 0; nt < 2; ++nt) {
    int c = ((wbase + nt*16) >> 3) + (hi >> 1);
    f4 bb = nt ? bb1 : bb0;
#pragma unroll
    for (int rt = 0; rt < 4; ++rt) {
      int row = rt*16 + r15;
      h4 p;
#pragma unroll
      for (int d = 0; d < 4; ++d) p[d] = (_Float16)fmaxf(acc[rt][nt][d] + bb[d], 0.f);
      *(h4*)(sm + hb + row*256 + ((c ^ (row & 7)) << 4) + bo2) = p;
    }
  }
}
// raw acc -> h[hb] (no bias/relu)
__device__ __forceinline__ void hw4r(char* sm, int hb, int wbase, const f4 acc[4][2],
                                     int r15, int hi) {
  int bo2 = (hi & 1) * 8;
#pragma unroll
  for (int nt = 0; nt < 2; ++nt) {
    int c = ((wbase + nt*16) >> 3) + (hi >> 1);
#pragma unroll
    for (int rt = 0; rt < 4; ++rt) {
      int row = rt*16 + r15;
      h4 p;
#pragma unroll
      for (int d = 0; d < 4; ++d) p[d] = (_Float16)acc[rt][nt][d];
      *(h4*)(sm + hb + row*256 + ((c ^ (row & 7)) << 4) + bo2) = p;
    }
  }
}

// out = acc + dec_bout + skip(h[hskip]) -> trbuf f32 at h[htr] (32KB span) -> global.
// Caller must __syncthreads() BEFORE (trbuf aliases last-read h buffers).
__device__ __forceinline__ void epi_store(char* sm, int hskip, int htr, int wbase,
                                          const f4 acc[4][2], const float* bl,
                                          float* dst, int rstride,
                                          int tid, int r15, int hi) {
  f4 bb0 = *(const f4*)(bl + 512 + wbase + hi*4);
  f4 bb1 = *(const f4*)(bl + 512 + wbase + 16 + hi*4);
  int bo2 = (hi & 1) * 8;
#pragma unroll
  for (int nt = 0; nt < 2; ++nt) {
    int c = ((wbase + nt*16) >> 3) + (hi >> 1);
    int q = (wbase >> 2) + nt*4 + hi;
    f4 bb = nt ? bb1 : bb0;
#pragma unroll
    for (int rt = 0; rt < 4; ++rt) {
      int row = rt*16 + r15;
      h4 sk = *(const h4*)(sm + hskip + row*256 + ((c ^ (row & 7)) << 4) + bo2);
      f4 v;
#pragma unroll
      for (int d = 0; d < 4; ++d) v[d] = acc[rt][nt][d] + bb[d] + (float)sk[d];
      *(f4*)(sm + htr + row*512 + ((q ^ ((row & 7) << 2)) << 4)) = v;
    }
  }
  __syncthreads();
#pragma unroll
  for (int i = 0; i < 8; ++i) {
    int idx = i*256 + tid, row = idx >> 5, q = idx & 31;
    f4 v = *(const f4*)(sm + htr + row*512 + ((q ^ ((row & 7) << 2)) << 4));
    *(f4*)(dst + (size_t)row*rstride + q*4) = v;
  }
}

#define LAYD(HIN, HOUT, BW, BO) do {                                 \
    mmF4s(sm, HIN, BW, acc, r15, hi);                                \
    hw4s(sm, HOUT, wbase, acc, bl, BO, r15, hi);                     \
    __syncthreads();                                                 \
  } while (0)

// ---------------- prep kernels ----------------

__global__ __launch_bounds__(512) void k_prep(
    const float* __restrict__ encW, const float* __restrict__ encWout,
    const float* __restrict__ decW, const float* __restrict__ decWout,
    const float* __restrict__ L,
    _Float16* __restrict__ wt, float* __restrict__ ach) {
  __shared__ float chA[441], chB[441];
  int m = blockIdx.y, tid = threadIdx.x;
  if (m == 10) {                                  // serial L-power chain
    if (blockIdx.x != 0) return;
    if (tid < 441) chA[tid] = L[tid];
    __syncthreads();
    for (int s = 0; s < 50; ++s) {
      if (tid < 441) ach[s*441 + tid] = chA[tid];
      if (s == 49) break;
      if (tid < 441) {
        int i = tid / 21, j = tid % 21; float a = 0.f;
        for (int k = 0; k < 21; ++k) a += chA[i*21 + k] * L[k*21 + j];
        chB[tid] = a;
      }
      __syncthreads();
      if (tid < 441) chA[tid] = chB[tid];
      __syncthreads();
    }
    return;
  }
  int idx = blockIdx.x*512 + tid;
  if (idx >= 16384) return;
  const float* src; _Float16* dst;
  if (m < 4)       { src = encW + m*16384;     dst = wt + WT_ENCW + m*16384; }
  else if (m == 4) { src = encWout;            dst = wt + WT_ENCWOUT; }
  else if (m < 9)  { src = decW + (m-5)*16384; dst = wt + WT_DECW + (m-5)*16384; }
  else             { src = decWout;            dst = wt + WT_DECWOUT; }
  int n = idx >> 7, k = idx & 127;
  dst[idx] = (_Float16)src[k*128 + n];            // W^T[n][k]
}

// block s<50: Mfull_s = WencI @ L^{s+1} @ WdecI ; s==50: Wcomb
__global__ __launch_bounds__(512) void k_aux(
    const float* __restrict__ ach, const float* __restrict__ wencI,
    const float* __restrict__ wdecI,
    _Float16* __restrict__ mfull, _Float16* __restrict__ wt) {
  __shared__ float T1[2688];
  __shared__ float sa[441];
  int s = blockIdx.x, t = threadIdx.x;
  if (s < 50) {
    if (t < 441) sa[t] = ach[s*441 + t];
    __syncthreads();
    for (int idx = t; idx < 2688; idx += 512) {
      int k = idx / 21, j = idx % 21;
      float a = 0.f;
      for (int u = 0; u < 21; ++u) a += wencI[k*21 + u] * sa[u*21 + j];
      T1[idx] = a;
    }
  } else {
    for (int idx = t; idx < 2688; idx += 512) T1[idx] = wencI[idx];
  }
  __syncthreads();
  _Float16* dst = (s < 50) ? (mfull + (size_t)s*16384) : (wt + WT_COMB);
  for (int idx = t; idx < 16384; idx += 512) {    // M^T[n][k]
    int n = idx >> 7, k = idx & 127;
    float a = 0.f;
    for (int j = 0; j < 21; ++j) a += T1[k*21 + j] * wdecI[j*128 + n];
    dst[idx] = (_Float16)a;
  }
}

// ---------------- encoder: x -> pe image + compact pet0 ----------------

__global__ __launch_bounds__(256, 2) void k_enc(
    const float* __restrict__ x, const _Float16* __restrict__ wt,
    const float* __restrict__ enc_b, const float* __restrict__ enc_bout,
    _Float16* __restrict__ pe_ws, _Float16* __restrict__ pet0) {
  __shared__ char sm[LDSE];
  float* bl = (float*)(sm + 49152);
  int tid = threadIdx.x, lane = tid & 63;
  int r15 = lane & 15, hi = lane >> 4;
  int wbase = (tid >> 6) * 32;
  h8 B0[8], B1[8], B2[8], B3[8], B4[8];
  loadW(B0, wt + WT_ENCW,           wbase, r15, hi);
  loadW(B1, wt + WT_ENCW + 16384,   wbase, r15, hi);
  loadW(B2, wt + WT_ENCW + 2*16384, wbase, r15, hi);
  loadW(B3, wt + WT_ENCW + 3*16384, wbase, r15, hi);
  loadW(B4, wt + WT_ENCWOUT,        wbase, r15, hi);
  PIN(B0); PIN(B1); PIN(B2); PIN(B3); PIN(B4);
  bl[tid] = enc_b[tid]; bl[256 + tid] = enc_b[256 + tid];
  if (tid < 128) bl[512 + tid] = enc_bout[tid];
  f4 acc[4][2];

  for (int t = blockIdx.x; t < NT64; t += gridDim.x) {
    size_t rb = (size_t)t * 64;
#pragma unroll
    for (int i = 0; i < 4; ++i) {                 // stage x -> h0 (enc skip)
      int idx = i*256 + tid, rl = idx >> 4, c = idx & 15;
      const float* s = x + (rb + rl)*128 + c*8;
      f4 v0 = *(const f4*)s, v1 = *(const f4*)(s + 4);
      *(h8*)(sm + H0 + hsw(rl, c)) = cvt8(v0, v1);
    }
    __syncthreads();
    LAYD(H0, H1, B0, 0); LAYD(H1, H2, B1, 128);
    LAYD(H2, H1, B2, 256); LAYD(H1, H2, B3, 384);
    mmF4s(sm, H2, B4, acc, r15, hi);              // encWout
    // pe = acc + bout + x(h0) -> H1 (f16)
    {
      f4 bb0 = *(const f4*)(bl + 512 + wbase + hi*4);
      f4 bb1 = *(const f4*)(bl + 512 + wbase + 16 + hi*4);
      int bo2 = (hi & 1) * 8;
#pragma unroll
      for (int nt = 0; nt < 2; ++nt) {
        int c = ((wbase + nt*16) >> 3) + (hi >> 1);
        f4 bb = nt ? bb1 : bb0;
#pragma unroll
        for (int rt = 0; rt < 4; ++rt) {
          int row = rt*16 + r15;
          int soff = row*256 + ((c ^ (row & 7)) << 4) + bo2;
          h4 sk = *(const h4*)(sm + H0 + soff);
          h4 p;
#pragma unroll
          for (int d = 0; d < 4; ++d) p[d] = (_Float16)(acc[rt][nt][d] + bb[d] + (float)sk[d]);
          *(h4*)(sm + H1 + soff) = p;
        }
      }
    }
    __syncthreads();
    {                                             // dump pe image + compact pet0
      char* g = (char*)(pe_ws) + (size_t)t*16384;
#pragma unroll
      for (int i = 0; i < 4; ++i) {
        int idx = i*256 + tid, off = idx*16;
        f4 v = *(const f4*)(sm + H1 + off);
        *(f4*)(g + off) = v;
        int rl = idx >> 4, slot = idx & 15;
        size_t rg = rb + (size_t)rl;
        if (rg % 51u == 0u) {                     // t=0 sample: b = rg/51
          int c = slot ^ (rl & 7);                // unswizzle -> chunk-linear
          *(f4*)((char*)pet0 + (rg/51u)*256 + c*16) = v;
        }
      }
    }
  }
}

// ---------------- dec tiles + pred units in one kernel ----------------

__global__ __launch_bounds__(256, 2) void k_decpred(
    const _Float16* __restrict__ wt, const _Float16* __restrict__ pe_ws,
    const _Float16* __restrict__ pet0, const _Float16* __restrict__ mfull,
    const float* __restrict__ dec_b, const float* __restrict__ dec_bout,
    float* __restrict__ out1, float* __restrict__ out2, float* __restrict__ out3) {
  __shared__ char sm[LDSD];
  float* bl = (float*)(sm + 65536);
  int tid = threadIdx.x, lane = tid & 63;
  int r15 = lane & 15, hi = lane >> 4;
  int wbase = (tid >> 6) * 32;
  h8 B0[8], B1[8], B2[8], B3[8], B4[8];
  loadW(B0, wt + WT_DECW,           wbase, r15, hi);
  loadW(B1, wt + WT_DECW + 16384,   wbase, r15, hi);
  loadW(B2, wt + WT_DECW + 2*16384, wbase, r15, hi);
  loadW(B3, wt + WT_DECW + 3*16384, wbase, r15, hi);
  loadW(B4, wt + WT_DECWOUT,        wbase, r15, hi);
  PIN(B0); PIN(B1); PIN(B2); PIN(B3); PIN(B4);
  bl[tid] = dec_b[tid]; bl[256 + tid] = dec_b[256 + tid];
  if (tid < 128) bl[512 + tid] = dec_bout[tid];
  f4 acc[4][2];

  for (int u = blockIdx.x; u < NUNITS; u += gridDim.x) {
    __syncthreads();                              // protect h bufs from prev-unit reads
    if (u < NT64) {
      // ---------- dec tile: pe -> out2 ; pd=pe@comb -> out1 ----------
      const char* src = (const char*)pe_ws + (size_t)u*16384;
      float* d2 = out2 + (size_t)u*64*128;
      float* d1 = out1 + (size_t)u*64*128;
#pragma unroll
      for (int i = 0; i < 4; ++i) {               // stage pe -> H0 (input+skip)
        int off = (i*256 + tid)*16;
        *(f4*)(sm + H0 + off) = *(const f4*)(src + off);
      }
      __syncthreads();
      // stream B: dec(pe)
      LAYD(H0, H1, B0, 0); LAYD(H1, H2, B1, 128);
      LAYD(H2, H1, B2, 256); LAYD(H1, H2, B3, 384);
      mmF4s(sm, H2, B4, acc, r15, hi);
      __syncthreads();                            // H2 reads done (trbuf = H1+H2)
      epi_store(sm, H0, H1, wbase, acc, bl, d2, 128, tid, r15, hi);
      // pd = pe @ comb (transient weights)
      {
        h8 Bc[8];
        loadW(Bc, wt + WT_COMB, wbase, r15, hi);
        mmF4s(sm, H0, Bc, acc, r15, hi);
      }
      hw4r(sm, H3, wbase, acc, r15, hi);          // pd -> H3 (input+skip)
      __syncthreads();
      // stream A: dec(pd)
      LAYD(H3, H0, B0, 0); LAYD(H0, H1, B1, 128);
      LAYD(H1, H0, B2, 256); LAYD(H0, H1, B3, 384);
      mmF4s(sm, H1, B4, acc, r15, hi);
      __syncthreads();                            // H1 reads done (trbuf = H0+H1)
      epi_store(sm, H3, H0, wbase, acc, bl, d1, 128, tid, r15, hi);
    } else {
      // ---------- pred unit: pet0 tile x 5 Koopman steps ----------
      int p = u - NT64, rtile = p / 10, chunk = p % 10;
#pragma unroll
      for (int i = 0; i < 4; ++i) {               // stage pet0 -> H0 (persistent)
        int idx = i*256 + tid, rl = idx >> 4, c = idx & 15;
        f4 v = *(const f4*)((const char*)pet0 + (size_t)(rtile*64 + rl)*256 + c*16);
        *(f4*)(sm + H0 + hsw(rl, c)) = v;
      }
      __syncthreads();
      for (int s = chunk*5; s < chunk*5 + 5; ++s) {
        {
          h8 Bm[8];
          loadW(Bm, mfull + (size_t)s*16384, wbase, r15, hi);
          mmF4s(sm, H0, Bm, acc, r15, hi);        // di = pet0 @ Mfull_s
        }
        hw4r(sm, H1, wbase, acc, r15, hi);        // di -> H1 (input+skip)
        __syncthreads();
        LAYD(H1, H2, B0, 0); LAYD(H2, H3, B1, 128);
        LAYD(H3, H2, B2, 256); LAYD(H2, H3, B3, 384);
        mmF4s(sm, H3, B4, acc, r15, hi);
        __syncthreads();                          // H3 reads done (trbuf = H2+H3)
        // rows row -> out3[((rtile*64+row)*50 + s)*128]
        epi_store(sm, H1, H2, wbase, acc, bl,
                  out3 + ((size_t)rtile*64*50 + s)*128, 50*128, tid, r15, hi);
        __syncthreads();                          // trbuf reads done before next s
      }
    }
  }
}

// ---------------- launch ----------------

extern "C" void kernel_launch(void* const* d_in, const int* in_sizes, int n_in,
                              void* d_out, int out_size, void* d_ws, size_t ws_size,
                              hipStream_t stream) {
  const float* x        = (const float*)d_in[0];
  const float* encW     = (const float*)d_in[1];
  const float* enc_b    = (const float*)d_in[2];
  const float* encWout  = (const float*)d_in[3];
  const float* enc_bout = (const float*)d_in[4];
  const float* decW     = (const float*)d_in[5];
  const float* dec_b    = (const float*)d_in[6];
  const float* decWout  = (const float*)d_in[7];
  const float* dec_bout = (const float*)d_in[8];
  const float* wencI    = (const float*)d_in[9];
  const float* L        = (const float*)d_in[10];
  const float* wdecI    = (const float*)d_in[11];

  char* ws = (char*)d_ws;
  _Float16* wt    = (_Float16*)ws;
  _Float16* mfull = (_Float16*)(ws + MFULL_OFF_B);
  float*    ach   = (float*)(ws + ACH_OFF_B);
  _Float16* pe_ws = (_Float16*)(ws + PE_OFF_B);
  _Float16* pet0  = (_Float16*)(ws + PET0_OFF_B);

  float* out1 = (float*)d_out;                       // autoencoder_output
  float* out2 = out1 + (size_t)ROWS_AUTO*128;        // outer_auto_output
  float* out3 = out2 + (size_t)ROWS_AUTO*128;        // predictions [2048][50][128]

  hipLaunchKernelGGL(k_prep, dim3(32, 11), dim3(512), 0, stream,
                     encW, encWout, decW, decWout, L, wt, ach);
  hipLaunchKernelGGL(k_aux, dim3(51), dim3(512), 0, stream,
                     ach, wencI, wdecI, mfull, wt);
  hipLaunchKernelGGL(k_enc, dim3(512), dim3(256), 0, stream,
                     x, wt, enc_b, enc_bout, pe_ws, pet0);
  hipLaunchKernelGGL(k_decpred, dim3(512), dim3(256), 0, stream,
                     wt, pe_ws, pet0, mfull, dec_b, dec_bout, out1, out2, out3);
}